// Round 6
// baseline (8463.110 us; speedup 1.0000x reference)
//
#include <hip/hip_runtime.h>
#include <cstdint>
#include <cstddef>

#define Mdim 1024
#define Ndim 4096
#define Bdim 16
#define SMax 512
#define KKv  32
#define NIT  8
#define NBLK 256
#define PQ   8     // proxy row chunks (128 rows each)

struct Prm {
  const float* Y; const float* A;
  float* At; float* G; float* Gi; float* V; float* T; float* Si;
  float* PP; float* Rres; float* Bv; float* XKval; int* XKcol;
  int* Cols; int* Flags; int* Sold; int* Snew; int* Done;
  int* Cnt; int* Gen; float* out;
};

// sense-reversing grid barrier: device-scope atomics + agent fences
__device__ __forceinline__ void gridbar(int* cnt, int* gen, int tid){
  __syncthreads();
  if (tid == 0){
    __threadfence();
    int g = __hip_atomic_load(gen, __ATOMIC_RELAXED, __HIP_MEMORY_SCOPE_AGENT);
    if (__hip_atomic_fetch_add(cnt, 1, __ATOMIC_ACQ_REL, __HIP_MEMORY_SCOPE_AGENT) == NBLK - 1){
      __hip_atomic_store(cnt, 0, __ATOMIC_RELAXED, __HIP_MEMORY_SCOPE_AGENT);
      __hip_atomic_fetch_add(gen, 1, __ATOMIC_RELEASE, __HIP_MEMORY_SCOPE_AGENT);
    } else {
      while (__hip_atomic_load(gen, __ATOMIC_ACQUIRE, __HIP_MEMORY_SCOPE_AGENT) == g)
        __builtin_amdgcn_s_sleep(4);
    }
    __threadfence();
  }
  __syncthreads();
}

// out[r] = sgn*(Mat@vec)[r] + add[r]; rows strided by wave (4 waves), 4-row ILP
__device__ __forceinline__ void gemv_pass(const float* Mat, const float* vec, float* outv,
                                          const float* addv, float sgn, int s1, int w, int lane){
  int ncol = (s1 + 63) >> 6;
  for (int base = w; base < s1; base += 16){
    int rA = base, rB = base + 4, rC = base + 8, rD = base + 12;
    const float* pA = Mat + (size_t)rA * SMax;
    const float* pB = Mat + (size_t)((rB < s1) ? rB : rA) * SMax;
    const float* pC = Mat + (size_t)((rC < s1) ? rC : rA) * SMax;
    const float* pD = Mat + (size_t)((rD < s1) ? rD : rA) * SMax;
    float aA = 0, aB = 0, aC = 0, aD = 0;
    for (int c = 0; c < ncol; ++c){
      int idx = lane + 64 * c;
      float v = vec[idx];
      aA = fmaf(pA[idx], v, aA);
      aB = fmaf(pB[idx], v, aB);
      aC = fmaf(pC[idx], v, aC);
      aD = fmaf(pD[idx], v, aD);
    }
    #pragma unroll
    for (int off = 32; off > 0; off >>= 1){
      aA += __shfl_xor(aA, off); aB += __shfl_xor(aB, off);
      aC += __shfl_xor(aC, off); aD += __shfl_xor(aD, off);
    }
    if (lane == 0){
      outv[rA] = sgn * aA + (addv ? addv[rA] : 0.0f);
      if (rB < s1) outv[rB] = sgn * aB + (addv ? addv[rB] : 0.0f);
      if (rC < s1) outv[rC] = sgn * aC + (addv ? addv[rC] : 0.0f);
      if (rD < s1) outv[rD] = sgn * aD + (addv ? addv[rD] : 0.0f);
    }
  }
}

__global__ __launch_bounds__(256, 1) void k_cosamp(Prm p){
  __shared__ __align__(16) char smraw[49920];
  float* sm = (float*)smraw;
  const int tid = threadIdx.x, bid = blockIdx.x;
  const int lane = tid & 63, w = tid >> 6;
  int* cnt = p.Cnt; int* gen = p.Gen;

  // ================= phase 0: init + transpose A -> At =================
  for (int t2 = bid * 256 + tid; t2 < Bdim * Ndim; t2 += 65536) p.Flags[t2] = 0;
  for (int t2 = bid * 256 + tid; t2 < Bdim * Mdim; t2 += 65536) p.Rres[t2] = p.Y[t2];
  if (bid == 0 && tid < Bdim){ p.Sold[tid] = 0; p.Snew[tid] = 0; p.Done[tid] = 0; }
  {
    int tx = tid & 31, ty = tid >> 5;   // 32 x 8
    for (int task = bid; task < (Ndim / 32) * (Mdim / 32); task += NBLK){
      int jt = task >> 5, it2 = task & 31;
      int j0 = jt * 32, i0 = it2 * 32;
      __syncthreads();
      #pragma unroll
      for (int r = 0; r < 32; r += 8)
        sm[(ty + r) * 33 + tx] = p.A[(size_t)(i0 + ty + r) * Ndim + j0 + tx];
      __syncthreads();
      #pragma unroll
      for (int r = 0; r < 32; r += 8)
        p.At[(size_t)(j0 + ty + r) * Mdim + i0 + tx] = sm[tx * 33 + ty + r];
    }
  }
  gridbar(cnt, gen, tid);

  for (int it = 0; it < NIT; ++it){
    // ================= proxy: PP[rq][b][j] partials (128 active blocks) =================
    if (bid < PQ * 16){
      int rq = bid >> 4, jb = bid & 15;     // 8 chunks of 128 rows x 16 j-blocks of 256
      for (int e = tid; e < Bdim * 128; e += 256){
        int b = e >> 7, i = e & 127;
        sm[e] = p.Rres[b * Mdim + rq * 128 + i];
      }
      __syncthreads();
      int j = jb * 256 + tid;
      float acc[Bdim];
      #pragma unroll
      for (int b = 0; b < Bdim; ++b) acc[b] = 0.0f;
      for (int i = 0; i < 128; ++i){
        float a = p.A[(size_t)(rq * 128 + i) * Ndim + j];
        #pragma unroll
        for (int b = 0; b < Bdim; ++b) acc[b] = fmaf(a, sm[b * 128 + i], acc[b]);
      }
      #pragma unroll
      for (int b = 0; b < Bdim; ++b) p.PP[(size_t)(rq * Bdim + b) * Ndim + j] = acc[b];
    }
    gridbar(cnt, gen, tid);
    // ================= topk: top-64 of |proxy|, support update =================
    if (bid < Bdim && !p.Done[bid]){
      int b = bid;
      unsigned long long* keys = (unsigned long long*)sm;
      for (int j = tid; j < Ndim; j += 256){
        float v = 0.0f;
        #pragma unroll
        for (int q = 0; q < PQ; ++q) v += p.PP[(size_t)(q * Bdim + b) * Ndim + j];
        keys[j] = ((unsigned long long)__float_as_uint(fabsf(v)) << 32) | (unsigned)j;
      }
      __syncthreads();
      for (int ksz = 2; ksz <= Ndim; ksz <<= 1){
        for (int jsz = ksz >> 1; jsz > 0; jsz >>= 1){
          for (int t2 = tid; t2 < Ndim / 2; t2 += 256){
            int i = 2 * t2 - (t2 & (jsz - 1));
            int ixj = i ^ jsz;
            unsigned long long a = keys[i], c = keys[ixj];
            bool sw = ((i & ksz) == 0) ? (a < c) : (a > c);
            if (sw){ keys[i] = c; keys[ixj] = a; }
          }
          __syncthreads();
        }
      }
      if (tid < 64){
        int s = p.Snew[b];
        if (tid == 0) p.Sold[b] = s;
        int j = (int)(keys[tid] & 0xFFFFFFFFu);
        int notin = (p.Flags[b * Ndim + j] == 0) ? 1 : 0;
        unsigned long long bal = __ballot(notin);
        if (notin){
          int pos = s + __popcll(bal & ((1ull << tid) - 1ull));
          p.Flags[b * Ndim + j] = 1;
          p.Cols[b * SMax + pos] = j;
        }
        if (tid == 0) p.Snew[b] = s + (int)__popcll(bal);
      }
    }
    gridbar(cnt, gen, tid);
    // ================= gram: new rows/cols of G + rhs =================
    {
      int b = bid >> 4, pg = bid & 15;
      if (!p.Done[b]){
        int s0 = p.Sold[b], s1 = p.Snew[b];
        int p0 = s0 + pg * 4;
        if (p0 < s1){
          int np = min(4, s1 - p0);
          float* Ap = sm;   // [4][1024]
          for (int e = tid; e < 4 * Mdim; e += 256){
            int pi = e >> 10, i = e & (Mdim - 1);
            Ap[e] = (p0 + pi < s1) ? p.At[(size_t)p.Cols[b * SMax + p0 + pi] * Mdim + i] : 0.0f;
          }
          __syncthreads();
          for (int q = w; q <= s1; q += 4){   // q == s1 => rhs (dot with y)
            const float* aq = (q < s1) ? (p.At + (size_t)p.Cols[b * SMax + q] * Mdim)
                                       : (p.Y + (size_t)b * Mdim);
            float a0 = 0, a1 = 0, a2 = 0, a3 = 0;
            #pragma unroll
            for (int c = 0; c < 16; ++c){
              float v = aq[lane + 64 * c];
              a0 = fmaf(v, Ap[0 * Mdim + lane + 64 * c], a0);
              a1 = fmaf(v, Ap[1 * Mdim + lane + 64 * c], a1);
              a2 = fmaf(v, Ap[2 * Mdim + lane + 64 * c], a2);
              a3 = fmaf(v, Ap[3 * Mdim + lane + 64 * c], a3);
            }
            #pragma unroll
            for (int off = 32; off > 0; off >>= 1){
              a0 += __shfl_xor(a0, off); a1 += __shfl_xor(a1, off);
              a2 += __shfl_xor(a2, off); a3 += __shfl_xor(a3, off);
            }
            if (lane == 0){
              float av[4] = {a0, a1, a2, a3};
              for (int r = 0; r < np; ++r){
                int pp = p0 + r;
                if (q < s1){
                  p.G[((size_t)b * SMax + pp) * SMax + q] = av[r];
                  p.G[((size_t)b * SMax + q) * SMax + pp] = av[r];
                } else {
                  p.Bv[(size_t)b * SMax + pp] = av[r];
                }
              }
            }
          }
        }
      }
    }
    gridbar(cnt, gen, tid);
    // ================= V = Gi_old @ B =================
    if (it > 0){
      int b = bid & 15, i0 = (bid >> 4) * 64;
      if (!p.Done[b]){
        int s0 = p.Sold[b], s1 = p.Snew[b], nn = s1 - s0;
        if (i0 < s0){
          float* Gt = sm; float* Bt = sm + 4160;
          int tx = tid & 15, ty = tid >> 4;
          float acc[4][4];
          #pragma unroll
          for (int r = 0; r < 4; ++r)
            #pragma unroll
            for (int c = 0; c < 4; ++c) acc[r][c] = 0.0f;
          for (int k0 = 0; k0 < s0; k0 += 64){
            for (int e = tid; e < 4096; e += 256){
              int r = e >> 6, c = e & 63;
              Gt[r * 65 + c] = p.Gi[((size_t)b * SMax + i0 + r) * SMax + k0 + c];
              Bt[r * 65 + c] = (k0 + r < s0 && c < nn) ? p.G[((size_t)b * SMax + k0 + r) * SMax + s0 + c] : 0.0f;
            }
            __syncthreads();
            for (int d = 0; d < 64; ++d){
              float gv[4], bv[4];
              #pragma unroll
              for (int r = 0; r < 4; ++r) gv[r] = Gt[(ty * 4 + r) * 65 + d];
              #pragma unroll
              for (int c = 0; c < 4; ++c) bv[c] = Bt[d * 65 + tx * 4 + c];
              #pragma unroll
              for (int r = 0; r < 4; ++r)
                #pragma unroll
                for (int c = 0; c < 4; ++c) acc[r][c] = fmaf(gv[r], bv[c], acc[r][c]);
            }
            __syncthreads();
          }
          for (int r = 0; r < 4; ++r)
            for (int c = 0; c < 4; ++c){
              int i = i0 + ty * 4 + r, cc = tx * 4 + c;
              if (i < s0 && cc < nn)
                p.V[((size_t)b * SMax + i) * 64 + cc] = acc[r][c];
            }
        }
      }
      gridbar(cnt, gen, tid);
    }
    // ================= schur: S = Gnn - B^T V ; Si = S^{-1} (LDS reused) =================
    if (bid < Bdim && !p.Done[bid]){
      int b = bid;
      int s0 = p.Sold[b], s1 = p.Snew[b], nn = s1 - s0;
      float* Bt = sm; float* Vt = sm + 4160;
      int tx = tid & 15, ty = tid >> 4;
      float acc[4][4];
      #pragma unroll
      for (int r = 0; r < 4; ++r)
        #pragma unroll
        for (int c = 0; c < 4; ++c) acc[r][c] = 0.0f;
      for (int k0 = 0; k0 < s0; k0 += 64){
        for (int e = tid; e < 4096; e += 256){
          int r = e >> 6, c = e & 63;
          bool ok = (k0 + r < s0) && (c < nn);
          Bt[r * 65 + c] = ok ? p.G[((size_t)b * SMax + k0 + r) * SMax + s0 + c] : 0.0f;
          Vt[r * 65 + c] = ok ? p.V[((size_t)b * SMax + k0 + r) * 64 + c] : 0.0f;
        }
        __syncthreads();
        for (int d = 0; d < 64; ++d){
          float bm[4], vv[4];
          #pragma unroll
          for (int r = 0; r < 4; ++r) bm[r] = Bt[d * 65 + ty * 4 + r];
          #pragma unroll
          for (int c = 0; c < 4; ++c) vv[c] = Vt[d * 65 + tx * 4 + c];
          #pragma unroll
          for (int r = 0; r < 4; ++r)
            #pragma unroll
            for (int c = 0; c < 4; ++c) acc[r][c] = fmaf(bm[r], vv[c], acc[r][c]);
        }
        __syncthreads();
      }
      // reuse Bt/Vt LDS as Sm/Wm (acc is in registers; last tile reads fenced above)
      float* Smx = sm; float* Wmx = sm + 4160;
      for (int r = 0; r < 4; ++r)
        for (int c = 0; c < 4; ++c){
          int rr = ty * 4 + r, cc = tx * 4 + c;
          float sval;
          if (rr < nn && cc < nn)
            sval = p.G[((size_t)b * SMax + s0 + rr) * SMax + s0 + cc] - acc[r][c];
          else
            sval = (rr == cc) ? 1.0f : 0.0f;
          Smx[rr * 65 + cc] = sval;
          Wmx[rr * 65 + cc] = (rr == cc) ? 1.0f : 0.0f;
        }
      __syncthreads();
      {
        int gi = tid & 63;
        int gc0 = (tid >> 6) * 16;
        for (int j = 0; j < 64; ++j){
          float rp = 1.0f / Smx[j * 65 + j];
          float f = Smx[gi * 65 + j] * rp;
          if (gi != j){
            #pragma unroll
            for (int cc = 0; cc < 16; ++cc){
              int c = gc0 + cc;
              if (c > j)
                Smx[gi * 65 + c] = fmaf(-f, Smx[j * 65 + c], Smx[gi * 65 + c]);
              else
                Wmx[gi * 65 + c] = fmaf(-f, Wmx[j * 65 + c], Wmx[gi * 65 + c]);
            }
          }
          __syncthreads();
        }
      }
      for (int e = tid; e < 4096; e += 256){
        int r = e >> 6, c = e & 63;
        p.Si[(size_t)b * 4096 + e] = Wmx[r * 65 + c] / Smx[r * 65 + r];
      }
    }
    gridbar(cnt, gen, tid);
    // ================= T = V @ Si =================
    if (it > 0){
      int b = bid & 15, i0 = (bid >> 4) * 64;
      if (!p.Done[b]){
        int s0 = p.Sold[b], s1 = p.Snew[b], nn = s1 - s0;
        if (i0 < s0){
          float* Vt = sm; float* Ss = sm + 4160;
          for (int e = tid; e < 4096; e += 256){
            int r = e >> 6, c = e & 63;
            Vt[r * 65 + c] = (i0 + r < s0 && c < nn) ? p.V[((size_t)b * SMax + i0 + r) * 64 + c] : 0.0f;
            Ss[r * 65 + c] = p.Si[(size_t)b * 4096 + e];
          }
          __syncthreads();
          int tx = tid & 15, ty = tid >> 4;
          float acc[4][4];
          #pragma unroll
          for (int r = 0; r < 4; ++r)
            #pragma unroll
            for (int c = 0; c < 4; ++c) acc[r][c] = 0.0f;
          for (int d = 0; d < 64; ++d){
            float vv[4], sv[4];
            #pragma unroll
            for (int r = 0; r < 4; ++r) vv[r] = Vt[(ty * 4 + r) * 65 + d];
            #pragma unroll
            for (int c = 0; c < 4; ++c) sv[c] = Ss[d * 65 + tx * 4 + c];
            #pragma unroll
            for (int r = 0; r < 4; ++r)
              #pragma unroll
              for (int c = 0; c < 4; ++c) acc[r][c] = fmaf(vv[r], sv[c], acc[r][c]);
          }
          for (int r = 0; r < 4; ++r)
            for (int c = 0; c < 4; ++c){
              int i = i0 + ty * 4 + r, dd = tx * 4 + c;
              if (i < s0 && dd < nn)
                p.T[((size_t)b * SMax + i) * 64 + dd] = acc[r][c];
            }
        }
      }
      gridbar(cnt, gen, tid);
    }
    // ================= upd: Gi <- bordered inverse =================
    {
      int nt = it + 1;
      int ntasks = Bdim * nt * nt;
      for (int task = bid; task < ntasks; task += NBLK){
        int b = task & 15, r0 = task >> 4;
        int i0 = (r0 / nt) * 64, k0 = (r0 % nt) * 64;
        if (!p.Done[b]){
          int s0 = p.Sold[b], s1 = p.Snew[b], nn = s1 - s0;
          if (i0 < s1 && k0 < s1){
            float* Tt = sm; float* Vk = sm + 4160; float* Tk = sm + 8320;
            __syncthreads();
            for (int e = tid; e < 4096; e += 256){
              int r = e >> 6, c = e & 63;
              Tt[r * 65 + c] = (i0 + r < s0 && c < nn) ? p.T[((size_t)b * SMax + i0 + r) * 64 + c] : 0.0f;
              Tk[r * 65 + c] = (k0 + r < s0 && c < nn) ? p.T[((size_t)b * SMax + k0 + r) * 64 + c] : 0.0f;
              Vk[r * 65 + c] = (k0 + r < s0 && c < nn) ? p.V[((size_t)b * SMax + k0 + r) * 64 + c] : 0.0f;
            }
            __syncthreads();
            int tx = tid & 15, ty = tid >> 4;
            float acc[4][4];
            #pragma unroll
            for (int r = 0; r < 4; ++r)
              #pragma unroll
              for (int c = 0; c < 4; ++c) acc[r][c] = 0.0f;
            for (int d = 0; d < 64; ++d){
              float tv[4], vv[4];
              #pragma unroll
              for (int r = 0; r < 4; ++r) tv[r] = Tt[(ty * 4 + r) * 65 + d];
              #pragma unroll
              for (int c = 0; c < 4; ++c) vv[c] = Vk[(tx * 4 + c) * 65 + d];
              #pragma unroll
              for (int r = 0; r < 4; ++r)
                #pragma unroll
                for (int c = 0; c < 4; ++c) acc[r][c] = fmaf(tv[r], vv[c], acc[r][c]);
            }
            for (int r = 0; r < 4; ++r)
              for (int c = 0; c < 4; ++c){
                int i = i0 + ty * 4 + r, k = k0 + tx * 4 + c;
                if (i < s1 && k < s1){
                  size_t idx = ((size_t)b * SMax + i) * SMax + k;
                  float val;
                  if (i < s0){
                    if (k < s0) val = p.Gi[idx] + acc[r][c];
                    else        val = -Tt[(ty * 4 + r) * 65 + (k - s0)];
                  } else {
                    if (k < s0) val = -Tk[(tx * 4 + c) * 65 + (i - s0)];
                    else        val = p.Si[(size_t)b * 4096 + (i - s0) * 64 + (k - s0)];
                  }
                  p.Gi[idx] = val;
                }
              }
          }
        }
      }
    }
    gridbar(cnt, gen, tid);
    // ================= solve: z (1 refinement) + top-32 + residual =================
    if (bid < Bdim && !p.Done[bid]){
      int b = bid;
      int s1 = p.Snew[b];
      float* vs = sm; float* z0 = sm + 512; float* r2v = sm + 1024;
      unsigned long long* sk = (unsigned long long*)(sm + 1536);
      float* xv = sm + 2560; int* xc = (int*)(sm + 2592); float* red = sm + 2624;
      for (int e = tid; e < SMax; e += 256){
        vs[e] = (e < s1) ? p.Bv[(size_t)b * SMax + e] : 0.0f;
        z0[e] = 0.0f; r2v[e] = 0.0f;
      }
      __syncthreads();
      const float* Gb  = p.G  + (size_t)b * SMax * SMax;
      const float* Gib = p.Gi + (size_t)b * SMax * SMax;
      gemv_pass(Gib, vs, z0, nullptr, 1.0f, s1, w, lane);
      __syncthreads();
      gemv_pass(Gb, z0, r2v, vs, -1.0f, s1, w, lane);
      __syncthreads();
      gemv_pass(Gib, r2v, z0, z0, 1.0f, s1, w, lane);
      __syncthreads();
      for (int e = tid; e < SMax; e += 256){
        unsigned long long key = 0;
        if (e < s1){
          float z = z0[e];
          key = ((unsigned long long)__float_as_uint(fabsf(z)) << 32)
              | ((unsigned long long)(4095 - p.Cols[b * SMax + e]) << 20) | (unsigned)e;
        }
        sk[e] = key;
      }
      __syncthreads();
      for (int ksz = 2; ksz <= SMax; ksz <<= 1){
        for (int jsz = ksz >> 1; jsz > 0; jsz >>= 1){
          for (int t2 = tid; t2 < SMax / 2; t2 += 256){
            int i = 2 * t2 - (t2 & (jsz - 1));
            int ixj = i ^ jsz;
            unsigned long long a = sk[i], c = sk[ixj];
            bool sw = ((i & ksz) == 0) ? (a < c) : (a > c);
            if (sw){ sk[i] = c; sk[ixj] = a; }
          }
          __syncthreads();
        }
      }
      if (tid < KKv){
        unsigned long long key = sk[tid];
        int pos = (int)(key & 0xFFFFFu);
        float v = z0[pos];
        xv[tid] = v;
        xc[tid] = p.Cols[b * SMax + pos];
        p.XKval[b * KKv + tid] = v;
        p.XKcol[b * KKv + tid] = xc[tid];
      }
      __syncthreads();
      float rr[4];
      #pragma unroll
      for (int q = 0; q < 4; ++q) rr[q] = p.Y[(size_t)b * Mdim + tid + 256 * q];
      for (int t2 = 0; t2 < KKv; ++t2){
        const float* colp = p.At + (size_t)xc[t2] * Mdim;
        float v = xv[t2];
        #pragma unroll
        for (int q = 0; q < 4; ++q) rr[q] = fmaf(-v, colp[tid + 256 * q], rr[q]);
      }
      float ss = 0.0f;
      #pragma unroll
      for (int q = 0; q < 4; ++q){
        p.Rres[(size_t)b * Mdim + tid + 256 * q] = rr[q];
        ss += rr[q] * rr[q];
      }
      #pragma unroll
      for (int off = 32; off > 0; off >>= 1) ss += __shfl_xor(ss, off);
      if (lane == 0) red[w] = ss;
      __syncthreads();
      if (tid == 0){
        float tot = red[0] + red[1] + red[2] + red[3];
        if (tot < 1e-12f) p.Done[b] = 1;
      }
    }
    gridbar(cnt, gen, tid);
  }
  // ================= output =================
  {
    int b = bid >> 4;
    float* xv = sm; int* xc = (int*)(sm + 64);
    if (tid < KKv){ xv[tid] = p.XKval[b * KKv + tid]; xc[tid] = p.XKcol[b * KKv + tid]; }
    __syncthreads();
    int j = (bid & 15) * 256 + tid;
    float v = 0.0f;
    #pragma unroll
    for (int t2 = 0; t2 < KKv; ++t2) v = (xc[t2] == j) ? xv[t2] : v;
    p.out[(size_t)b * Ndim + j] = v;
  }
}

// ----------------------------------------------------------------
extern "C" void kernel_launch(void* const* d_in, const int* in_sizes, int n_in,
                              void* d_out, int out_size, void* d_ws, size_t ws_size,
                              hipStream_t stream){
  const float* Y = (const float*)d_in[0];   // [B][M]
  const float* A = (const float*)d_in[1];   // [M][N]
  float* ws = (float*)d_ws;
  size_t off = 0;
  float* At   = ws + off; off += (size_t)Ndim * Mdim;
  float* G    = ws + off; off += (size_t)Bdim * SMax * SMax;
  float* Gi   = ws + off; off += (size_t)Bdim * SMax * SMax;
  float* V    = ws + off; off += (size_t)Bdim * SMax * 64;
  float* T    = ws + off; off += (size_t)Bdim * SMax * 64;
  float* Si   = ws + off; off += (size_t)Bdim * 64 * 64;
  float* PP   = ws + off; off += (size_t)PQ * Bdim * Ndim;
  float* Rres = ws + off; off += (size_t)Bdim * Mdim;
  float* Bv   = ws + off; off += (size_t)Bdim * SMax;
  float* XKval = ws + off; off += (size_t)Bdim * KKv;
  int* XKcol = (int*)(ws + off); off += (size_t)Bdim * KKv;
  int* Cols  = (int*)(ws + off); off += (size_t)Bdim * SMax;
  int* Flags = (int*)(ws + off); off += (size_t)Bdim * Ndim;
  int* Sold  = (int*)(ws + off); off += Bdim;
  int* Snew  = (int*)(ws + off); off += Bdim;
  int* Done  = (int*)(ws + off); off += Bdim;
  int* Bar   = (int*)(ws + off); off += 32;   // Cnt at [0], Gen at [16] (separate lines)

  hipMemsetAsync((void*)Bar, 0, 32 * sizeof(int), stream);
  Prm prm{Y, A, At, G, Gi, V, T, Si, PP, Rres, Bv, XKval, XKcol,
          Cols, Flags, Sold, Snew, Done, Bar, Bar + 16, (float*)d_out};
  k_cosamp<<<NBLK, 256, 0, stream>>>(prm);
}

// Round 7
// 2127.489 us; speedup vs baseline: 3.9780x; 3.9780x over previous
//
#include <hip/hip_runtime.h>
#include <cstdint>
#include <cstddef>

#define Mdim 1024
#define Ndim 4096
#define Bdim 16
#define SMax 512
#define K2v  64
#define KKv  32
#define NIT  8
#define PQ   8     // proxy row chunks

// ---------------------------------------------------------------- init
__global__ __launch_bounds__(256) void k_init(const float* __restrict__ Y, float* __restrict__ Rres,
        int* __restrict__ Flags, int* __restrict__ Sold, int* __restrict__ Snew, int* __restrict__ Done){
  int idx = blockIdx.x * 256 + threadIdx.x;
  int total = Bdim * Ndim;
  for (int t = idx; t < total; t += gridDim.x * 256){
    Flags[t] = 0;
    if (t < Bdim * Mdim) Rres[t] = Y[t];
    if (t < Bdim){ Sold[t] = 0; Snew[t] = 0; Done[t] = 0; }
  }
}

// ---------------------------------------------------------------- transpose A[M][N] -> At[N][M]
__global__ __launch_bounds__(256) void k_transpose(const float* __restrict__ A, float* __restrict__ At){
  __shared__ float tile[32][33];
  int j0 = blockIdx.x * 32, i0 = blockIdx.y * 32;
  int tx = threadIdx.x, ty = threadIdx.y;   // 32 x 8
  for (int r = 0; r < 32; r += 8)
    tile[ty + r][tx] = A[(size_t)(i0 + ty + r) * Ndim + (j0 + tx)];
  __syncthreads();
  for (int r = 0; r < 32; r += 8)
    At[(size_t)(j0 + ty + r) * Mdim + (i0 + tx)] = tile[tx][ty + r];
}

// ---------------------------------------------------------------- proxy partials
__global__ __launch_bounds__(256) void k_proxy(const float* __restrict__ A, const float* __restrict__ Rres,
        float* __restrict__ PP){
  int j = blockIdx.x * 256 + threadIdx.x;
  int rq = blockIdx.y;                       // 8 chunks of 128 rows
  __shared__ float Rq[Bdim][128];
  for (int e = threadIdx.x; e < Bdim * 128; e += 256){
    int b = e >> 7, i = e & 127;
    Rq[b][i] = Rres[b * Mdim + rq * 128 + i];
  }
  __syncthreads();
  float acc[Bdim];
  #pragma unroll
  for (int b = 0; b < Bdim; ++b) acc[b] = 0.0f;
  for (int i = 0; i < 128; ++i){
    float a = A[(size_t)(rq * 128 + i) * Ndim + j];
    #pragma unroll
    for (int b = 0; b < Bdim; ++b) acc[b] = fmaf(a, Rq[b][i], acc[b]);
  }
  #pragma unroll
  for (int b = 0; b < Bdim; ++b)
    PP[(size_t)(rq * Bdim + b) * Ndim + j] = acc[b];
}

// ---------------------------------------------------------------- top-64 of |proxy|, update support
__global__ __launch_bounds__(1024) void k_topk(const float* __restrict__ PP, int* __restrict__ Flags,
        int* __restrict__ Cols, int* __restrict__ Sold, int* __restrict__ Snew, const int* __restrict__ Done){
  int b = blockIdx.x;
  if (Done[b]) return;
  __shared__ unsigned long long keys[Ndim];   // 32KB
  int tid = threadIdx.x;
  for (int j = tid; j < Ndim; j += 1024){
    float v = 0.0f;
    #pragma unroll
    for (int q = 0; q < PQ; ++q) v += PP[(size_t)(q * Bdim + b) * Ndim + j];
    unsigned int ab = __float_as_uint(fabsf(v));
    keys[j] = ((unsigned long long)ab << 32) | (unsigned int)j;
  }
  __syncthreads();
  for (int ksz = 2; ksz <= Ndim; ksz <<= 1){
    for (int jsz = ksz >> 1; jsz > 0; jsz >>= 1){
      for (int t = tid; t < Ndim / 2; t += 1024){
        int i = 2 * t - (t & (jsz - 1));
        int ixj = i ^ jsz;
        unsigned long long a = keys[i], c = keys[ixj];
        bool sw = ((i & ksz) == 0) ? (a < c) : (a > c);
        if (sw){ keys[i] = c; keys[ixj] = a; }
      }
      __syncthreads();
    }
  }
  if (tid < 64){
    int s = Snew[b];
    if (tid == 0) Sold[b] = s;
    int j = (int)(keys[tid] & 0xFFFFFFFFu);
    int notin = (Flags[b * Ndim + j] == 0) ? 1 : 0;
    unsigned long long bal = __ballot(notin);
    if (notin){
      int pos = s + __popcll(bal & ((1ull << tid) - 1ull));
      Flags[b * Ndim + j] = 1;
      Cols[b * SMax + pos] = j;
    }
    if (tid == 0) Snew[b] = s + (int)__popcll(bal);
  }
}

// ---------------------------------------------------------------- incremental Gram rows + rhs entries
__global__ __launch_bounds__(256) void k_gram(const float* __restrict__ At, const float* __restrict__ Y,
        float* __restrict__ G, float* __restrict__ Bv,
        const int* __restrict__ Cols, const int* __restrict__ Sold, const int* __restrict__ Snew,
        const int* __restrict__ Done){
  int b = blockIdx.x;
  if (Done[b]) return;
  int s0 = Sold[b], s1 = Snew[b];
  int p0 = s0 + (int)blockIdx.y * 4;
  if (p0 >= s1) return;
  int np = min(4, s1 - p0);
  __shared__ float Ap[4][Mdim];   // 16KB
  int tid = threadIdx.x;
  for (int e = tid; e < 4 * Mdim; e += 256){
    int pi = e >> 10, i = e & (Mdim - 1);
    Ap[pi][i] = (p0 + pi < s1) ? At[(size_t)Cols[b * SMax + p0 + pi] * Mdim + i] : 0.0f;
  }
  __syncthreads();
  int w = tid >> 6, lane = tid & 63;
  for (int q = w; q <= s1; q += 4){    // q == s1 => rhs (dot with y)
    const float* aq = (q < s1) ? (At + (size_t)Cols[b * SMax + q] * Mdim) : (Y + (size_t)b * Mdim);
    float a0 = 0, a1 = 0, a2 = 0, a3 = 0;
    #pragma unroll
    for (int c = 0; c < 16; ++c){
      float v = aq[lane + 64 * c];
      a0 = fmaf(v, Ap[0][lane + 64 * c], a0);
      a1 = fmaf(v, Ap[1][lane + 64 * c], a1);
      a2 = fmaf(v, Ap[2][lane + 64 * c], a2);
      a3 = fmaf(v, Ap[3][lane + 64 * c], a3);
    }
    #pragma unroll
    for (int off = 32; off > 0; off >>= 1){
      a0 += __shfl_xor(a0, off);
      a1 += __shfl_xor(a1, off);
      a2 += __shfl_xor(a2, off);
      a3 += __shfl_xor(a3, off);
    }
    if (lane == 0){
      float av[4] = {a0, a1, a2, a3};
      for (int r = 0; r < np; ++r){
        int p = p0 + r;
        if (q < s1){
          G[((size_t)b * SMax + p) * SMax + q] = av[r];
          G[((size_t)b * SMax + q) * SMax + p] = av[r];
        } else {
          Bv[(size_t)b * SMax + p] = av[r];
        }
      }
    }
  }
}

// ---------------------------------------------------------------- V = Gi_old @ B
__global__ __launch_bounds__(256) void k_V(const float* __restrict__ G, const float* __restrict__ Gi,
        float* __restrict__ V, const int* __restrict__ Sold, const int* __restrict__ Snew,
        const int* __restrict__ Done){
  int b = blockIdx.x;
  if (Done[b]) return;
  int s0 = Sold[b], s1 = Snew[b], nn = s1 - s0;
  int i0 = (int)blockIdx.y * 64;
  if (i0 >= s0) return;
  __shared__ float Gt[64][65];
  __shared__ float Bt[64][65];
  int tid = threadIdx.x;
  int tx = tid & 15, ty = tid >> 4;
  float acc[4][4];
  #pragma unroll
  for (int r = 0; r < 4; ++r)
    #pragma unroll
    for (int c = 0; c < 4; ++c) acc[r][c] = 0.0f;
  for (int k0 = 0; k0 < s0; k0 += 64){
    for (int e = tid; e < 64 * 64; e += 256){
      int r = e >> 6, c = e & 63;
      Gt[r][c] = Gi[((size_t)b * SMax + i0 + r) * SMax + k0 + c];
      Bt[r][c] = (k0 + r < s0 && c < nn) ? G[((size_t)b * SMax + k0 + r) * SMax + s0 + c] : 0.0f;
    }
    __syncthreads();
    for (int d = 0; d < 64; ++d){
      float gv[4], bv[4];
      #pragma unroll
      for (int r = 0; r < 4; ++r) gv[r] = Gt[ty * 4 + r][d];
      #pragma unroll
      for (int c = 0; c < 4; ++c) bv[c] = Bt[d][tx * 4 + c];
      #pragma unroll
      for (int r = 0; r < 4; ++r)
        #pragma unroll
        for (int c = 0; c < 4; ++c) acc[r][c] = fmaf(gv[r], bv[c], acc[r][c]);
    }
    __syncthreads();
  }
  for (int r = 0; r < 4; ++r)
    for (int c = 0; c < 4; ++c){
      int i = i0 + ty * 4 + r, cc = tx * 4 + c;
      if (i < s0 && cc < nn)
        V[((size_t)b * SMax + i) * K2v + cc] = acc[r][c];
    }
}

// ---------------------------------------------------------------- register-resident 64x64 Gauss-Jordan
// (template recursion forces compile-time indices -> guaranteed VGPR residency)
template<int J, int I> struct RowU {
  static __device__ __forceinline__ void go(float (&s)[64], float (&w)[64]){
    if constexpr (I != J){
      float f = __uint_as_float((unsigned)__builtin_amdgcn_readlane((int)__float_as_uint(s[I]), J));
      s[I] = fmaf(-f, s[J], s[I]);
      w[I] = fmaf(-f, w[J], w[I]);
    }
    if constexpr (I + 1 < 64) RowU<J, I + 1>::go(s, w);
  }
};
template<int J> struct PivT {
  static __device__ __forceinline__ void go(float (&s)[64], float (&w)[64]){
    float d = __uint_as_float((unsigned)__builtin_amdgcn_readlane((int)__float_as_uint(s[J]), J));
    float rp = 1.0f / d;
    s[J] *= rp;
    w[J] *= rp;
    RowU<J, 0>::go(s, w);
    if constexpr (J + 1 < 64) PivT<J + 1>::go(s, w);
  }
};

// ---------------------------------------------------------------- S = Gnn - B^T V (tiled), Si = S^{-1}
__global__ __launch_bounds__(256, 1) void k_schur(const float* __restrict__ G, const float* __restrict__ V,
        float* __restrict__ Si, const int* __restrict__ Sold, const int* __restrict__ Snew,
        const int* __restrict__ Done){
  int b = blockIdx.x;
  if (Done[b]) return;
  int s0 = Sold[b], s1 = Snew[b], nn = s1 - s0;
  __shared__ float Sm[64][65];
  __shared__ float Bt[64][65];
  __shared__ float Vt[64][65];
  int tid = threadIdx.x;
  int tx = tid & 15, ty = tid >> 4;
  float acc[4][4];
  #pragma unroll
  for (int r = 0; r < 4; ++r)
    #pragma unroll
    for (int c = 0; c < 4; ++c) acc[r][c] = 0.0f;
  // S accumulation: acc[r][c] = sum_k B[k][r0+r] * V[k][c0+c], LDS-tiled
  for (int k0 = 0; k0 < s0; k0 += 64){
    for (int e = tid; e < 64 * 64; e += 256){
      int r = e >> 6, c = e & 63;
      bool ok = (k0 + r < s0) && (c < nn);
      Bt[r][c] = ok ? G[((size_t)b * SMax + k0 + r) * SMax + s0 + c] : 0.0f;
      Vt[r][c] = ok ? V[((size_t)b * SMax + k0 + r) * K2v + c] : 0.0f;
    }
    __syncthreads();
    for (int d = 0; d < 64; ++d){
      float bm[4], vv[4];
      #pragma unroll
      for (int r = 0; r < 4; ++r) bm[r] = Bt[d][ty * 4 + r];
      #pragma unroll
      for (int c = 0; c < 4; ++c) vv[c] = Vt[d][tx * 4 + c];
      #pragma unroll
      for (int r = 0; r < 4; ++r)
        #pragma unroll
        for (int c = 0; c < 4; ++c) acc[r][c] = fmaf(bm[r], vv[c], acc[r][c]);
    }
    __syncthreads();
  }
  // write S (identity-padded) into LDS
  for (int r = 0; r < 4; ++r)
    for (int c = 0; c < 4; ++c){
      int rr = ty * 4 + r, cc = tx * 4 + c;
      float sval;
      if (rr < nn && cc < nn)
        sval = G[((size_t)b * SMax + s0 + rr) * SMax + s0 + cc] - acc[r][c];
      else
        sval = (rr == cc) ? 1.0f : 0.0f;
      Sm[rr][cc] = sval;
    }
  __syncthreads();
  // single-wave register GJ: lane = column; zero barriers, zero LDS traffic
  if (tid < 64){
    float s[64], w[64];
    #pragma unroll
    for (int r = 0; r < 64; ++r){
      s[r] = Sm[r][tid];
      w[r] = (r == tid) ? 1.0f : 0.0f;
    }
    PivT<0>::go(s, w);
    #pragma unroll
    for (int r = 0; r < 64; ++r)
      Si[(size_t)b * K2v * K2v + r * K2v + tid] = w[r];
  }
}

// ---------------------------------------------------------------- T = V @ Si
__global__ __launch_bounds__(256) void k_T(const float* __restrict__ V, const float* __restrict__ Si,
        float* __restrict__ T, const int* __restrict__ Sold, const int* __restrict__ Snew,
        const int* __restrict__ Done){
  int b = blockIdx.x;
  if (Done[b]) return;
  int s0 = Sold[b], s1 = Snew[b], nn = s1 - s0;
  int i0 = (int)blockIdx.y * 64;
  if (i0 >= s0) return;
  __shared__ float Vt[64][65];
  __shared__ float Ss[64][65];
  int tid = threadIdx.x;
  for (int e = tid; e < 64 * 64; e += 256){
    int r = e >> 6, c = e & 63;
    Vt[r][c] = (i0 + r < s0 && c < nn) ? V[((size_t)b * SMax + i0 + r) * K2v + c] : 0.0f;
    Ss[r][c] = Si[(size_t)b * K2v * K2v + e];
  }
  __syncthreads();
  int tx = tid & 15, ty = tid >> 4;
  float acc[4][4];
  #pragma unroll
  for (int r = 0; r < 4; ++r)
    #pragma unroll
    for (int c = 0; c < 4; ++c) acc[r][c] = 0.0f;
  for (int d = 0; d < 64; ++d){
    float vv[4], sv[4];
    #pragma unroll
    for (int r = 0; r < 4; ++r) vv[r] = Vt[ty * 4 + r][d];
    #pragma unroll
    for (int c = 0; c < 4; ++c) sv[c] = Ss[d][tx * 4 + c];
    #pragma unroll
    for (int r = 0; r < 4; ++r)
      #pragma unroll
      for (int c = 0; c < 4; ++c) acc[r][c] = fmaf(vv[r], sv[c], acc[r][c]);
  }
  for (int r = 0; r < 4; ++r)
    for (int c = 0; c < 4; ++c){
      int i = i0 + ty * 4 + r, dd = tx * 4 + c;
      if (i < s0 && dd < nn)
        T[((size_t)b * SMax + i) * K2v + dd] = acc[r][c];
    }
}

// ---------------------------------------------------------------- Gi <- bordered inverse update (in place)
__global__ __launch_bounds__(256) void k_upd(float* __restrict__ Gi, const float* __restrict__ T,
        const float* __restrict__ V, const float* __restrict__ Si,
        const int* __restrict__ Sold, const int* __restrict__ Snew, const int* __restrict__ Done){
  int b = blockIdx.x;
  if (Done[b]) return;
  int s0 = Sold[b], s1 = Snew[b];
  int i0 = (int)blockIdx.y * 64, k0 = (int)blockIdx.z * 64;
  if (i0 >= s1 || k0 >= s1) return;
  int nn = s1 - s0;
  __shared__ float Tt[64][65];
  __shared__ float Vk[64][65];
  __shared__ float Tk[64][65];
  int tid = threadIdx.x;
  for (int e = tid; e < 64 * 64; e += 256){
    int r = e >> 6, c = e & 63;
    Tt[r][c] = (i0 + r < s0 && c < nn) ? T[((size_t)b * SMax + i0 + r) * K2v + c] : 0.0f;
    Tk[r][c] = (k0 + r < s0 && c < nn) ? T[((size_t)b * SMax + k0 + r) * K2v + c] : 0.0f;
    Vk[r][c] = (k0 + r < s0 && c < nn) ? V[((size_t)b * SMax + k0 + r) * K2v + c] : 0.0f;
  }
  __syncthreads();
  int tx = tid & 15, ty = tid >> 4;
  float acc[4][4];
  #pragma unroll
  for (int r = 0; r < 4; ++r)
    #pragma unroll
    for (int c = 0; c < 4; ++c) acc[r][c] = 0.0f;
  for (int d = 0; d < 64; ++d){
    float tv[4], vv[4];
    #pragma unroll
    for (int r = 0; r < 4; ++r) tv[r] = Tt[ty * 4 + r][d];
    #pragma unroll
    for (int c = 0; c < 4; ++c) vv[c] = Vk[tx * 4 + c][d];
    #pragma unroll
    for (int r = 0; r < 4; ++r)
      #pragma unroll
      for (int c = 0; c < 4; ++c) acc[r][c] = fmaf(tv[r], vv[c], acc[r][c]);
  }
  for (int r = 0; r < 4; ++r)
    for (int c = 0; c < 4; ++c){
      int i = i0 + ty * 4 + r, k = k0 + tx * 4 + c;
      if (i < s1 && k < s1){
        size_t idx = ((size_t)b * SMax + i) * SMax + k;
        float val;
        if (i < s0){
          if (k < s0) val = Gi[idx] + acc[r][c];
          else        val = -Tt[ty * 4 + r][k - s0];
        } else {
          if (k < s0) val = -Tk[tx * 4 + c][i - s0];
          else        val = Si[(size_t)b * K2v * K2v + (i - s0) * K2v + (k - s0)];
        }
        Gi[idx] = val;
      }
    }
}

// ---------------------------------------------------------------- fused solve + top-32 + residual
__global__ __launch_bounds__(512) void k_solve(const float* __restrict__ G, const float* __restrict__ Gi,
        const float* __restrict__ Bv, const float* __restrict__ At, const float* __restrict__ Y,
        const int* __restrict__ Cols, const int* __restrict__ Snew, int* __restrict__ Done,
        float* __restrict__ XKval, int* __restrict__ XKcol, float* __restrict__ Rres){
  int b = blockIdx.x;
  if (Done[b]) return;
  int s1 = Snew[b];
  __shared__ float vs[SMax];
  __shared__ float z0[SMax];
  __shared__ float r2[SMax];
  __shared__ unsigned long long sk[SMax];
  __shared__ float xv[KKv];
  __shared__ int   xc[KKv];
  __shared__ float red[8];
  int tid = threadIdx.x;
  int w = tid >> 6, lane = tid & 63;
  vs[tid] = (tid < s1) ? Bv[(size_t)b * SMax + tid] : 0.0f;
  z0[tid] = 0.0f;
  r2[tid] = 0.0f;
  __syncthreads();
  #define GEMV_PASS(MAT, VEC, STORE)                                            \
    for (int base = w; base < s1; base += 32){                                  \
      int r1i = base, r2i = base + 8, r3i = base + 16, r4i = base + 24;         \
      const float* p1 = (MAT) + ((size_t)b * SMax + r1i) * SMax;                \
      const float* p2 = (MAT) + ((size_t)b * SMax + (r2i < s1 ? r2i : r1i)) * SMax; \
      const float* p3 = (MAT) + ((size_t)b * SMax + (r3i < s1 ? r3i : r1i)) * SMax; \
      const float* p4 = (MAT) + ((size_t)b * SMax + (r4i < s1 ? r4i : r1i)) * SMax; \
      float a1 = 0, a2 = 0, a3 = 0, a4 = 0;                                     \
      _Pragma("unroll")                                                         \
      for (int c = 0; c < 8; ++c){                                              \
        float v = (VEC)[lane + 64 * c];                                         \
        a1 = fmaf(p1[lane + 64 * c], v, a1);                                    \
        a2 = fmaf(p2[lane + 64 * c], v, a2);                                    \
        a3 = fmaf(p3[lane + 64 * c], v, a3);                                    \
        a4 = fmaf(p4[lane + 64 * c], v, a4);                                    \
      }                                                                         \
      _Pragma("unroll")                                                         \
      for (int off = 32; off > 0; off >>= 1){                                   \
        a1 += __shfl_xor(a1, off); a2 += __shfl_xor(a2, off);                   \
        a3 += __shfl_xor(a3, off); a4 += __shfl_xor(a4, off);                   \
      }                                                                         \
      if (lane == 0){                                                           \
        { int i = r1i; float a = a1; STORE; }                                   \
        if (r2i < s1){ int i = r2i; float a = a2; STORE; }                      \
        if (r3i < s1){ int i = r3i; float a = a3; STORE; }                      \
        if (r4i < s1){ int i = r4i; float a = a4; STORE; }                      \
      }                                                                         \
    }
  GEMV_PASS(Gi, vs, z0[i] = a)
  __syncthreads();
  GEMV_PASS(G, z0, r2[i] = vs[i] - a)
  __syncthreads();
  GEMV_PASS(Gi, r2, z0[i] = z0[i] + a)
  __syncthreads();
  #undef GEMV_PASS
  {
    unsigned long long key = 0;
    if (tid < s1){
      float z = z0[tid];
      unsigned int ab = __float_as_uint(fabsf(z));
      int col = Cols[b * SMax + tid];
      key = ((unsigned long long)ab << 32) | ((unsigned long long)(4095 - col) << 20) | (unsigned int)tid;
    }
    sk[tid] = key;
  }
  __syncthreads();
  for (int ksz = 2; ksz <= SMax; ksz <<= 1){
    for (int jsz = ksz >> 1; jsz > 0; jsz >>= 1){
      for (int t = tid; t < SMax / 2; t += 512){
        int i = 2 * t - (t & (jsz - 1));
        int ixj = i ^ jsz;
        unsigned long long a = sk[i], c = sk[ixj];
        bool sw = ((i & ksz) == 0) ? (a < c) : (a > c);
        if (sw){ sk[i] = c; sk[ixj] = a; }
      }
      __syncthreads();
    }
  }
  if (tid < KKv){
    unsigned long long key = sk[tid];
    int p = (int)(key & 0xFFFFFu);
    float v = z0[p];
    xv[tid] = v;
    xc[tid] = Cols[b * SMax + p];
    XKval[b * KKv + tid] = v;
    XKcol[b * KKv + tid] = xc[tid];
  }
  __syncthreads();
  int i1 = tid, i2 = tid + 512;
  float ra = Y[(size_t)b * Mdim + i1];
  float rb = Y[(size_t)b * Mdim + i2];
  for (int t = 0; t < KKv; ++t){
    const float* colp = At + (size_t)xc[t] * Mdim;
    float v = xv[t];
    ra = fmaf(-v, colp[i1], ra);
    rb = fmaf(-v, colp[i2], rb);
  }
  Rres[(size_t)b * Mdim + i1] = ra;
  Rres[(size_t)b * Mdim + i2] = rb;
  float ss = ra * ra + rb * rb;
  #pragma unroll
  for (int off = 32; off > 0; off >>= 1) ss += __shfl_xor(ss, off);
  if (lane == 0) red[w] = ss;
  __syncthreads();
  if (tid == 0){
    float tot = 0;
    for (int q = 0; q < 8; ++q) tot += red[q];
    if (tot < 1e-12f) Done[b] = 1;
  }
}

// ---------------------------------------------------------------- dense output
__global__ __launch_bounds__(1024) void k_output(const float* __restrict__ XKval, const int* __restrict__ XKcol,
        float* __restrict__ out){
  int b = blockIdx.x;
  __shared__ float xv[KKv];
  __shared__ int   xc[KKv];
  if (threadIdx.x < KKv){
    xv[threadIdx.x] = XKval[b * KKv + threadIdx.x];
    xc[threadIdx.x] = XKcol[b * KKv + threadIdx.x];
  }
  __syncthreads();
  int j = blockIdx.y * 1024 + threadIdx.x;
  float v = 0.0f;
  #pragma unroll
  for (int t = 0; t < KKv; ++t) v = (xc[t] == j) ? xv[t] : v;
  out[(size_t)b * Ndim + j] = v;
}

// ----------------------------------------------------------------
extern "C" void kernel_launch(void* const* d_in, const int* in_sizes, int n_in,
                              void* d_out, int out_size, void* d_ws, size_t ws_size,
                              hipStream_t stream){
  const float* Y = (const float*)d_in[0];   // [B][M]
  const float* A = (const float*)d_in[1];   // [M][N]
  float* ws = (float*)d_ws;
  size_t off = 0;
  float* At   = ws + off; off += (size_t)Ndim * Mdim;
  float* G    = ws + off; off += (size_t)Bdim * SMax * SMax;
  float* Gi   = ws + off; off += (size_t)Bdim * SMax * SMax;
  float* V    = ws + off; off += (size_t)Bdim * SMax * K2v;
  float* T    = ws + off; off += (size_t)Bdim * SMax * K2v;
  float* Si   = ws + off; off += (size_t)Bdim * K2v * K2v;
  float* PP   = ws + off; off += (size_t)PQ * Bdim * Ndim;
  float* Rres = ws + off; off += (size_t)Bdim * Mdim;
  float* Bv   = ws + off; off += (size_t)Bdim * SMax;
  float* XKval = ws + off; off += (size_t)Bdim * KKv;
  int* XKcol = (int*)(ws + off); off += (size_t)Bdim * KKv;
  int* Cols  = (int*)(ws + off); off += (size_t)Bdim * SMax;
  int* Flags = (int*)(ws + off); off += (size_t)Bdim * Ndim;
  int* Sold  = (int*)(ws + off); off += Bdim;
  int* Snew  = (int*)(ws + off); off += Bdim;
  int* Done  = (int*)(ws + off); off += Bdim;

  k_init<<<256, 256, 0, stream>>>(Y, Rres, Flags, Sold, Snew, Done);
  k_transpose<<<dim3(Ndim / 32, Mdim / 32), dim3(32, 8), 0, stream>>>(A, At);
  for (int t = 0; t < NIT; ++t){
    k_proxy<<<dim3(Ndim / 256, PQ), 256, 0, stream>>>(A, Rres, PP);
    k_topk<<<Bdim, 1024, 0, stream>>>(PP, Flags, Cols, Sold, Snew, Done);
    k_gram<<<dim3(Bdim, 16), 256, 0, stream>>>(At, Y, G, Bv, Cols, Sold, Snew, Done);
    if (t > 0)
      k_V<<<dim3(Bdim, t), 256, 0, stream>>>(G, Gi, V, Sold, Snew, Done);
    k_schur<<<Bdim, 256, 0, stream>>>(G, V, Si, Sold, Snew, Done);
    if (t > 0)
      k_T<<<dim3(Bdim, t), 256, 0, stream>>>(V, Si, T, Sold, Snew, Done);
    k_upd<<<dim3(Bdim, t + 1, t + 1), 256, 0, stream>>>(Gi, T, V, Si, Sold, Snew, Done);
    k_solve<<<Bdim, 512, 0, stream>>>(G, Gi, Bv, At, Y, Cols, Snew, Done, XKval, XKcol, Rres);
  }
  k_output<<<dim3(Bdim, Ndim / 1024), 1024, 0, stream>>>(XKval, XKcol, (float*)d_out);
}

// Round 8
// 1833.105 us; speedup vs baseline: 4.6168x; 1.1606x over previous
//
#include <hip/hip_runtime.h>
#include <cstdint>
#include <cstddef>

#define Mdim 1024
#define Ndim 4096
#define Bdim 16
#define SMax 512
#define K2v  64
#define KKv  32
#define NIT  8
#define PQ   8     // proxy row chunks

// ---------------------------------------------------------------- init
__global__ __launch_bounds__(256) void k_init(const float* __restrict__ Y, float* __restrict__ Rres,
        int* __restrict__ Flags, int* __restrict__ Sold, int* __restrict__ Snew, int* __restrict__ Done){
  int idx = blockIdx.x * 256 + threadIdx.x;
  int total = Bdim * Ndim;
  for (int t = idx; t < total; t += gridDim.x * 256){
    Flags[t] = 0;
    if (t < Bdim * Mdim) Rres[t] = Y[t];
    if (t < Bdim){ Sold[t] = 0; Snew[t] = 0; Done[t] = 0; }
  }
}

// ---------------------------------------------------------------- transpose A[M][N] -> At[N][M]
__global__ __launch_bounds__(256) void k_transpose(const float* __restrict__ A, float* __restrict__ At){
  __shared__ float tile[32][33];
  int j0 = blockIdx.x * 32, i0 = blockIdx.y * 32;
  int tx = threadIdx.x, ty = threadIdx.y;   // 32 x 8
  for (int r = 0; r < 32; r += 8)
    tile[ty + r][tx] = A[(size_t)(i0 + ty + r) * Ndim + (j0 + tx)];
  __syncthreads();
  for (int r = 0; r < 32; r += 8)
    At[(size_t)(j0 + ty + r) * Mdim + (i0 + tx)] = tile[tx][ty + r];
}

// ---------------------------------------------------------------- proxy partials
__global__ __launch_bounds__(256) void k_proxy(const float* __restrict__ A, const float* __restrict__ Rres,
        float* __restrict__ PP){
  int j = blockIdx.x * 256 + threadIdx.x;
  int rq = blockIdx.y;                       // 8 chunks of 128 rows
  __shared__ float Rq[Bdim][128];
  for (int e = threadIdx.x; e < Bdim * 128; e += 256){
    int b = e >> 7, i = e & 127;
    Rq[b][i] = Rres[b * Mdim + rq * 128 + i];
  }
  __syncthreads();
  float acc[Bdim];
  #pragma unroll
  for (int b = 0; b < Bdim; ++b) acc[b] = 0.0f;
  for (int i = 0; i < 128; ++i){
    float a = A[(size_t)(rq * 128 + i) * Ndim + j];
    #pragma unroll
    for (int b = 0; b < Bdim; ++b) acc[b] = fmaf(a, Rq[b][i], acc[b]);
  }
  #pragma unroll
  for (int b = 0; b < Bdim; ++b)
    PP[(size_t)(rq * Bdim + b) * Ndim + j] = acc[b];
}

// ---------------------------------------------------------------- top-64 of |proxy|, update support
__global__ __launch_bounds__(1024) void k_topk(const float* __restrict__ PP, int* __restrict__ Flags,
        int* __restrict__ Cols, int* __restrict__ Sold, int* __restrict__ Snew, const int* __restrict__ Done){
  int b = blockIdx.x;
  if (Done[b]) return;
  __shared__ unsigned long long keys[Ndim];   // 32KB
  int tid = threadIdx.x;
  for (int j = tid; j < Ndim; j += 1024){
    float v = 0.0f;
    #pragma unroll
    for (int q = 0; q < PQ; ++q) v += PP[(size_t)(q * Bdim + b) * Ndim + j];
    unsigned int ab = __float_as_uint(fabsf(v));
    keys[j] = ((unsigned long long)ab << 32) | (unsigned int)j;
  }
  __syncthreads();
  for (int ksz = 2; ksz <= Ndim; ksz <<= 1){
    for (int jsz = ksz >> 1; jsz > 0; jsz >>= 1){
      for (int t = tid; t < Ndim / 2; t += 1024){
        int i = 2 * t - (t & (jsz - 1));
        int ixj = i ^ jsz;
        unsigned long long a = keys[i], c = keys[ixj];
        bool sw = ((i & ksz) == 0) ? (a < c) : (a > c);
        if (sw){ keys[i] = c; keys[ixj] = a; }
      }
      __syncthreads();
    }
  }
  if (tid < 64){
    int s = Snew[b];
    if (tid == 0) Sold[b] = s;
    int j = (int)(keys[tid] & 0xFFFFFFFFu);
    int notin = (Flags[b * Ndim + j] == 0) ? 1 : 0;
    unsigned long long bal = __ballot(notin);
    if (notin){
      int pos = s + __popcll(bal & ((1ull << tid) - 1ull));
      Flags[b * Ndim + j] = 1;
      Cols[b * SMax + pos] = j;
    }
    if (tid == 0) Snew[b] = s + (int)__popcll(bal);
  }
}

// ---------------------------------------------------------------- incremental Gram rows + rhs entries
__global__ __launch_bounds__(256) void k_gram(const float* __restrict__ At, const float* __restrict__ Y,
        float* __restrict__ G, float* __restrict__ Bv,
        const int* __restrict__ Cols, const int* __restrict__ Sold, const int* __restrict__ Snew,
        const int* __restrict__ Done){
  int b = blockIdx.x;
  if (Done[b]) return;
  int s0 = Sold[b], s1 = Snew[b];
  int p0 = s0 + (int)blockIdx.y * 4;
  if (p0 >= s1) return;
  int np = min(4, s1 - p0);
  __shared__ float Ap[4][Mdim];   // 16KB
  int tid = threadIdx.x;
  for (int e = tid; e < 4 * Mdim; e += 256){
    int pi = e >> 10, i = e & (Mdim - 1);
    Ap[pi][i] = (p0 + pi < s1) ? At[(size_t)Cols[b * SMax + p0 + pi] * Mdim + i] : 0.0f;
  }
  __syncthreads();
  int w = tid >> 6, lane = tid & 63;
  for (int q = w; q <= s1; q += 4){    // q == s1 => rhs (dot with y)
    const float* aq = (q < s1) ? (At + (size_t)Cols[b * SMax + q] * Mdim) : (Y + (size_t)b * Mdim);
    float a0 = 0, a1 = 0, a2 = 0, a3 = 0;
    #pragma unroll
    for (int c = 0; c < 16; ++c){
      float v = aq[lane + 64 * c];
      a0 = fmaf(v, Ap[0][lane + 64 * c], a0);
      a1 = fmaf(v, Ap[1][lane + 64 * c], a1);
      a2 = fmaf(v, Ap[2][lane + 64 * c], a2);
      a3 = fmaf(v, Ap[3][lane + 64 * c], a3);
    }
    #pragma unroll
    for (int off = 32; off > 0; off >>= 1){
      a0 += __shfl_xor(a0, off);
      a1 += __shfl_xor(a1, off);
      a2 += __shfl_xor(a2, off);
      a3 += __shfl_xor(a3, off);
    }
    if (lane == 0){
      float av[4] = {a0, a1, a2, a3};
      for (int r = 0; r < np; ++r){
        int p = p0 + r;
        if (q < s1){
          G[((size_t)b * SMax + p) * SMax + q] = av[r];
          G[((size_t)b * SMax + q) * SMax + p] = av[r];
        } else {
          Bv[(size_t)b * SMax + p] = av[r];
        }
      }
    }
  }
}

// ---------------------------------------------------------------- V = Gi_old @ B
__global__ __launch_bounds__(256) void k_V(const float* __restrict__ G, const float* __restrict__ Gi,
        float* __restrict__ V, const int* __restrict__ Sold, const int* __restrict__ Snew,
        const int* __restrict__ Done){
  int b = blockIdx.x;
  if (Done[b]) return;
  int s0 = Sold[b], s1 = Snew[b], nn = s1 - s0;
  int i0 = (int)blockIdx.y * 64;
  if (i0 >= s0) return;
  __shared__ float Gt[64][65];
  __shared__ float Bt[64][65];
  int tid = threadIdx.x;
  int tx = tid & 15, ty = tid >> 4;
  float acc[4][4];
  #pragma unroll
  for (int r = 0; r < 4; ++r)
    #pragma unroll
    for (int c = 0; c < 4; ++c) acc[r][c] = 0.0f;
  for (int k0 = 0; k0 < s0; k0 += 64){
    for (int e = tid; e < 64 * 64; e += 256){
      int r = e >> 6, c = e & 63;
      Gt[r][c] = Gi[((size_t)b * SMax + i0 + r) * SMax + k0 + c];
      Bt[r][c] = (k0 + r < s0 && c < nn) ? G[((size_t)b * SMax + k0 + r) * SMax + s0 + c] : 0.0f;
    }
    __syncthreads();
    for (int d = 0; d < 64; ++d){
      float gv[4], bv[4];
      #pragma unroll
      for (int r = 0; r < 4; ++r) gv[r] = Gt[ty * 4 + r][d];
      #pragma unroll
      for (int c = 0; c < 4; ++c) bv[c] = Bt[d][tx * 4 + c];
      #pragma unroll
      for (int r = 0; r < 4; ++r)
        #pragma unroll
        for (int c = 0; c < 4; ++c) acc[r][c] = fmaf(gv[r], bv[c], acc[r][c]);
    }
    __syncthreads();
  }
  for (int r = 0; r < 4; ++r)
    for (int c = 0; c < 4; ++c){
      int i = i0 + ty * 4 + r, cc = tx * 4 + c;
      if (i < s0 && cc < nn)
        V[((size_t)b * SMax + i) * K2v + cc] = acc[r][c];
    }
}

// ---------------------------------------------------------------- register-resident 64x64 Gauss-Jordan
template<int J, int I> struct RowU {
  static __device__ __forceinline__ void go(float (&s)[64], float (&w)[64]){
    if constexpr (I != J){
      float f = __uint_as_float((unsigned)__builtin_amdgcn_readlane((int)__float_as_uint(s[I]), J));
      s[I] = fmaf(-f, s[J], s[I]);
      w[I] = fmaf(-f, w[J], w[I]);
    }
    if constexpr (I + 1 < 64) RowU<J, I + 1>::go(s, w);
  }
};
template<int J> struct PivT {
  static __device__ __forceinline__ void go(float (&s)[64], float (&w)[64]){
    float d = __uint_as_float((unsigned)__builtin_amdgcn_readlane((int)__float_as_uint(s[J]), J));
    float rp = 1.0f / d;
    s[J] *= rp;
    w[J] *= rp;
    RowU<J, 0>::go(s, w);
    if constexpr (J + 1 < 64) PivT<J + 1>::go(s, w);
  }
};

// ---------------------------------------------------------------- S = Gnn - B^T V (tiled), Si = S^{-1}
__global__ __launch_bounds__(256, 1) void k_schur(const float* __restrict__ G, const float* __restrict__ V,
        float* __restrict__ Si, const int* __restrict__ Sold, const int* __restrict__ Snew,
        const int* __restrict__ Done){
  int b = blockIdx.x;
  if (Done[b]) return;
  int s0 = Sold[b], s1 = Snew[b], nn = s1 - s0;
  __shared__ float Sm[64][65];
  __shared__ float Bt[64][65];
  __shared__ float Vt[64][65];
  int tid = threadIdx.x;
  int tx = tid & 15, ty = tid >> 4;
  float acc[4][4];
  #pragma unroll
  for (int r = 0; r < 4; ++r)
    #pragma unroll
    for (int c = 0; c < 4; ++c) acc[r][c] = 0.0f;
  for (int k0 = 0; k0 < s0; k0 += 64){
    for (int e = tid; e < 64 * 64; e += 256){
      int r = e >> 6, c = e & 63;
      bool ok = (k0 + r < s0) && (c < nn);
      Bt[r][c] = ok ? G[((size_t)b * SMax + k0 + r) * SMax + s0 + c] : 0.0f;
      Vt[r][c] = ok ? V[((size_t)b * SMax + k0 + r) * K2v + c] : 0.0f;
    }
    __syncthreads();
    for (int d = 0; d < 64; ++d){
      float bm[4], vv[4];
      #pragma unroll
      for (int r = 0; r < 4; ++r) bm[r] = Bt[d][ty * 4 + r];
      #pragma unroll
      for (int c = 0; c < 4; ++c) vv[c] = Vt[d][tx * 4 + c];
      #pragma unroll
      for (int r = 0; r < 4; ++r)
        #pragma unroll
        for (int c = 0; c < 4; ++c) acc[r][c] = fmaf(bm[r], vv[c], acc[r][c]);
    }
    __syncthreads();
  }
  for (int r = 0; r < 4; ++r)
    for (int c = 0; c < 4; ++c){
      int rr = ty * 4 + r, cc = tx * 4 + c;
      float sval;
      if (rr < nn && cc < nn)
        sval = G[((size_t)b * SMax + s0 + rr) * SMax + s0 + cc] - acc[r][c];
      else
        sval = (rr == cc) ? 1.0f : 0.0f;
      Sm[rr][cc] = sval;
    }
  __syncthreads();
  // single-wave register GJ: lane = column; zero barriers, zero LDS traffic
  if (tid < 64){
    float s[64], w[64];
    #pragma unroll
    for (int r = 0; r < 64; ++r){
      s[r] = Sm[r][tid];
      w[r] = (r == tid) ? 1.0f : 0.0f;
    }
    PivT<0>::go(s, w);
    #pragma unroll
    for (int r = 0; r < 64; ++r)
      Si[(size_t)b * K2v * K2v + r * K2v + tid] = w[r];
  }
}

// ---------------------------------------------------------------- T = V @ Si
__global__ __launch_bounds__(256) void k_T(const float* __restrict__ V, const float* __restrict__ Si,
        float* __restrict__ T, const int* __restrict__ Sold, const int* __restrict__ Snew,
        const int* __restrict__ Done){
  int b = blockIdx.x;
  if (Done[b]) return;
  int s0 = Sold[b], s1 = Snew[b], nn = s1 - s0;
  int i0 = (int)blockIdx.y * 64;
  if (i0 >= s0) return;
  __shared__ float Vt[64][65];
  __shared__ float Ss[64][65];
  int tid = threadIdx.x;
  for (int e = tid; e < 64 * 64; e += 256){
    int r = e >> 6, c = e & 63;
    Vt[r][c] = (i0 + r < s0 && c < nn) ? V[((size_t)b * SMax + i0 + r) * K2v + c] : 0.0f;
    Ss[r][c] = Si[(size_t)b * K2v * K2v + e];
  }
  __syncthreads();
  int tx = tid & 15, ty = tid >> 4;
  float acc[4][4];
  #pragma unroll
  for (int r = 0; r < 4; ++r)
    #pragma unroll
    for (int c = 0; c < 4; ++c) acc[r][c] = 0.0f;
  for (int d = 0; d < 64; ++d){
    float vv[4], sv[4];
    #pragma unroll
    for (int r = 0; r < 4; ++r) vv[r] = Vt[ty * 4 + r][d];
    #pragma unroll
    for (int c = 0; c < 4; ++c) sv[c] = Ss[d][tx * 4 + c];
    #pragma unroll
    for (int r = 0; r < 4; ++r)
      #pragma unroll
      for (int c = 0; c < 4; ++c) acc[r][c] = fmaf(vv[r], sv[c], acc[r][c]);
  }
  for (int r = 0; r < 4; ++r)
    for (int c = 0; c < 4; ++c){
      int i = i0 + ty * 4 + r, dd = tx * 4 + c;
      if (i < s0 && dd < nn)
        T[((size_t)b * SMax + i) * K2v + dd] = acc[r][c];
    }
}

// ---------------------------------------------------------------- Gi <- bordered inverse update (in place)
__global__ __launch_bounds__(256) void k_upd(float* __restrict__ Gi, const float* __restrict__ T,
        const float* __restrict__ V, const float* __restrict__ Si,
        const int* __restrict__ Sold, const int* __restrict__ Snew, const int* __restrict__ Done){
  int b = blockIdx.x;
  if (Done[b]) return;
  int s0 = Sold[b], s1 = Snew[b];
  int i0 = (int)blockIdx.y * 64, k0 = (int)blockIdx.z * 64;
  if (i0 >= s1 || k0 >= s1) return;
  int nn = s1 - s0;
  __shared__ float Tt[64][65];
  __shared__ float Vk[64][65];
  __shared__ float Tk[64][65];
  int tid = threadIdx.x;
  for (int e = tid; e < 64 * 64; e += 256){
    int r = e >> 6, c = e & 63;
    Tt[r][c] = (i0 + r < s0 && c < nn) ? T[((size_t)b * SMax + i0 + r) * K2v + c] : 0.0f;
    Tk[r][c] = (k0 + r < s0 && c < nn) ? T[((size_t)b * SMax + k0 + r) * K2v + c] : 0.0f;
    Vk[r][c] = (k0 + r < s0 && c < nn) ? V[((size_t)b * SMax + k0 + r) * K2v + c] : 0.0f;
  }
  __syncthreads();
  int tx = tid & 15, ty = tid >> 4;
  float acc[4][4];
  #pragma unroll
  for (int r = 0; r < 4; ++r)
    #pragma unroll
    for (int c = 0; c < 4; ++c) acc[r][c] = 0.0f;
  for (int d = 0; d < 64; ++d){
    float tv[4], vv[4];
    #pragma unroll
    for (int r = 0; r < 4; ++r) tv[r] = Tt[ty * 4 + r][d];
    #pragma unroll
    for (int c = 0; c < 4; ++c) vv[c] = Vk[tx * 4 + c][d];
    #pragma unroll
    for (int r = 0; r < 4; ++r)
      #pragma unroll
      for (int c = 0; c < 4; ++c) acc[r][c] = fmaf(tv[r], vv[c], acc[r][c]);
  }
  for (int r = 0; r < 4; ++r)
    for (int c = 0; c < 4; ++c){
      int i = i0 + ty * 4 + r, k = k0 + tx * 4 + c;
      if (i < s1 && k < s1){
        size_t idx = ((size_t)b * SMax + i) * SMax + k;
        float val;
        if (i < s0){
          if (k < s0) val = Gi[idx] + acc[r][c];
          else        val = -Tt[ty * 4 + r][k - s0];
        } else {
          if (k < s0) val = -Tk[tx * 4 + c][i - s0];
          else        val = Si[(size_t)b * K2v * K2v + (i - s0) * K2v + (k - s0)];
        }
        Gi[idx] = val;
      }
    }
}

// ---------------------------------------------------------------- wide GEMV: out = sgn*(Mat@vec) + add
// grid (Bdim, 8): 64 rows per block; 4 waves x 4 groups x 4-row ILP
__global__ __launch_bounds__(256) void k_gemv(const float* __restrict__ Mat, const float* __restrict__ vecsrc,
        const float* __restrict__ addsrc, float* __restrict__ out, float sgn,
        const int* __restrict__ Snew, const int* __restrict__ Done){
  int b = blockIdx.x;
  if (Done[b]) return;
  int s1 = Snew[b];
  int i0 = (int)blockIdx.y * 64;
  if (i0 >= s1) return;
  __shared__ float vs[SMax];
  int tid = threadIdx.x;
  int w = tid >> 6, lane = tid & 63;
  vs[tid]       = (tid < s1)       ? vecsrc[(size_t)b * SMax + tid]       : 0.0f;
  vs[tid + 256] = (tid + 256 < s1) ? vecsrc[(size_t)b * SMax + tid + 256] : 0.0f;
  __syncthreads();
  #pragma unroll
  for (int g = 0; g < 4; ++g){
    int base = i0 + w * 16 + g * 4;         // 4 consecutive rows
    if (base >= s1) break;
    const float* p0 = Mat + ((size_t)b * SMax + base) * SMax;
    const float* p1 = Mat + ((size_t)b * SMax + (base + 1 < s1 ? base + 1 : base)) * SMax;
    const float* p2 = Mat + ((size_t)b * SMax + (base + 2 < s1 ? base + 2 : base)) * SMax;
    const float* p3 = Mat + ((size_t)b * SMax + (base + 3 < s1 ? base + 3 : base)) * SMax;
    float a0 = 0, a1 = 0, a2 = 0, a3 = 0;
    #pragma unroll
    for (int c = 0; c < 8; ++c){
      int idx = lane + 64 * c;
      float v = vs[idx];
      a0 = fmaf(p0[idx], v, a0);
      a1 = fmaf(p1[idx], v, a1);
      a2 = fmaf(p2[idx], v, a2);
      a3 = fmaf(p3[idx], v, a3);
    }
    #pragma unroll
    for (int off = 32; off > 0; off >>= 1){
      a0 += __shfl_xor(a0, off); a1 += __shfl_xor(a1, off);
      a2 += __shfl_xor(a2, off); a3 += __shfl_xor(a3, off);
    }
    if (lane == 0){
      float av[4] = {a0, a1, a2, a3};
      #pragma unroll
      for (int r = 0; r < 4; ++r){
        int i = base + r;
        if (i < s1)
          out[(size_t)b * SMax + i] = sgn * av[r] + (addsrc ? addsrc[(size_t)b * SMax + i] : 0.0f);
      }
    }
  }
}

// ---------------------------------------------------------------- top-32 threshold, new residual, convergence
__global__ __launch_bounds__(1024) void k_finish(const float* __restrict__ Zz, const float* __restrict__ At,
        const float* __restrict__ Y, const int* __restrict__ Cols, const int* __restrict__ Snew,
        int* __restrict__ Done, float* __restrict__ XKval, int* __restrict__ XKcol, float* __restrict__ Rres){
  int b = blockIdx.x;
  if (Done[b]) return;
  int s1 = Snew[b];
  __shared__ unsigned long long sk[SMax];
  __shared__ float xv[KKv];
  __shared__ int   xc[KKv];
  __shared__ float red[16];
  int tid = threadIdx.x;
  if (tid < SMax){
    unsigned long long key = 0;
    if (tid < s1){
      float z = Zz[(size_t)b * SMax + tid];
      unsigned int ab = __float_as_uint(fabsf(z));
      int col = Cols[b * SMax + tid];
      key = ((unsigned long long)ab << 32) | ((unsigned long long)(4095 - col) << 20) | (unsigned int)tid;
    }
    sk[tid] = key;
  }
  __syncthreads();
  for (int ksz = 2; ksz <= SMax; ksz <<= 1){
    for (int jsz = ksz >> 1; jsz > 0; jsz >>= 1){
      for (int t = tid; t < SMax / 2; t += 1024){
        int i = 2 * t - (t & (jsz - 1));
        int ixj = i ^ jsz;
        unsigned long long a = sk[i], c = sk[ixj];
        bool sw = ((i & ksz) == 0) ? (a < c) : (a > c);
        if (sw){ sk[i] = c; sk[ixj] = a; }
      }
      __syncthreads();
    }
  }
  if (tid < KKv){
    unsigned long long key = sk[tid];
    int p = (int)(key & 0xFFFFFu);
    float v = Zz[(size_t)b * SMax + p];
    xv[tid] = v;
    xc[tid] = Cols[b * SMax + p];
    XKval[b * KKv + tid] = v;
    XKcol[b * KKv + tid] = xc[tid];
  }
  __syncthreads();
  float r = Y[(size_t)b * Mdim + tid];
  for (int t = 0; t < KKv; ++t)
    r = fmaf(-xv[t], At[(size_t)xc[t] * Mdim + tid], r);
  Rres[(size_t)b * Mdim + tid] = r;
  float ss = r * r;
  #pragma unroll
  for (int off = 32; off > 0; off >>= 1) ss += __shfl_xor(ss, off);
  if ((tid & 63) == 0) red[tid >> 6] = ss;
  __syncthreads();
  if (tid == 0){
    float tot = 0;
    for (int w = 0; w < 16; ++w) tot += red[w];
    if (tot < 1e-12f) Done[b] = 1;
  }
}

// ---------------------------------------------------------------- dense output
__global__ __launch_bounds__(1024) void k_output(const float* __restrict__ XKval, const int* __restrict__ XKcol,
        float* __restrict__ out){
  int b = blockIdx.x;
  __shared__ float xv[KKv];
  __shared__ int   xc[KKv];
  if (threadIdx.x < KKv){
    xv[threadIdx.x] = XKval[b * KKv + threadIdx.x];
    xc[threadIdx.x] = XKcol[b * KKv + threadIdx.x];
  }
  __syncthreads();
  int j = blockIdx.y * 1024 + threadIdx.x;
  float v = 0.0f;
  #pragma unroll
  for (int t = 0; t < KKv; ++t) v = (xc[t] == j) ? xv[t] : v;
  out[(size_t)b * Ndim + j] = v;
}

// ----------------------------------------------------------------
extern "C" void kernel_launch(void* const* d_in, const int* in_sizes, int n_in,
                              void* d_out, int out_size, void* d_ws, size_t ws_size,
                              hipStream_t stream){
  const float* Y = (const float*)d_in[0];   // [B][M]
  const float* A = (const float*)d_in[1];   // [M][N]
  float* ws = (float*)d_ws;
  size_t off = 0;
  float* At   = ws + off; off += (size_t)Ndim * Mdim;
  float* G    = ws + off; off += (size_t)Bdim * SMax * SMax;
  float* Gi   = ws + off; off += (size_t)Bdim * SMax * SMax;
  float* V    = ws + off; off += (size_t)Bdim * SMax * K2v;
  float* T    = ws + off; off += (size_t)Bdim * SMax * K2v;
  float* Si   = ws + off; off += (size_t)Bdim * K2v * K2v;
  float* PP   = ws + off; off += (size_t)PQ * Bdim * Ndim;
  float* Rres = ws + off; off += (size_t)Bdim * Mdim;
  float* Bv   = ws + off; off += (size_t)Bdim * SMax;
  float* Z0   = ws + off; off += (size_t)Bdim * SMax;
  float* R2   = ws + off; off += (size_t)Bdim * SMax;
  float* Zz   = ws + off; off += (size_t)Bdim * SMax;
  float* XKval = ws + off; off += (size_t)Bdim * KKv;
  int* XKcol = (int*)(ws + off); off += (size_t)Bdim * KKv;
  int* Cols  = (int*)(ws + off); off += (size_t)Bdim * SMax;
  int* Flags = (int*)(ws + off); off += (size_t)Bdim * Ndim;
  int* Sold  = (int*)(ws + off); off += Bdim;
  int* Snew  = (int*)(ws + off); off += Bdim;
  int* Done  = (int*)(ws + off); off += Bdim;

  k_init<<<256, 256, 0, stream>>>(Y, Rres, Flags, Sold, Snew, Done);
  k_transpose<<<dim3(Ndim / 32, Mdim / 32), dim3(32, 8), 0, stream>>>(A, At);
  for (int t = 0; t < NIT; ++t){
    k_proxy<<<dim3(Ndim / 256, PQ), 256, 0, stream>>>(A, Rres, PP);
    k_topk<<<Bdim, 1024, 0, stream>>>(PP, Flags, Cols, Sold, Snew, Done);
    k_gram<<<dim3(Bdim, 16), 256, 0, stream>>>(At, Y, G, Bv, Cols, Sold, Snew, Done);
    if (t > 0)
      k_V<<<dim3(Bdim, t), 256, 0, stream>>>(G, Gi, V, Sold, Snew, Done);
    k_schur<<<Bdim, 256, 0, stream>>>(G, V, Si, Sold, Snew, Done);
    if (t > 0)
      k_T<<<dim3(Bdim, t), 256, 0, stream>>>(V, Si, T, Sold, Snew, Done);
    k_upd<<<dim3(Bdim, t + 1, t + 1), 256, 0, stream>>>(Gi, T, V, Si, Sold, Snew, Done);
    k_gemv<<<dim3(Bdim, 8), 256, 0, stream>>>(Gi, Bv, nullptr, Z0, 1.0f, Snew, Done);
    k_gemv<<<dim3(Bdim, 8), 256, 0, stream>>>(G, Z0, Bv, R2, -1.0f, Snew, Done);
    k_gemv<<<dim3(Bdim, 8), 256, 0, stream>>>(Gi, R2, Z0, Zz, 1.0f, Snew, Done);
    k_finish<<<Bdim, 1024, 0, stream>>>(Zz, At, Y, Cols, Snew, Done, XKval, XKcol, Rres);
  }
  k_output<<<dim3(Bdim, Ndim / 1024), 1024, 0, stream>>>(XKval, XKcol, (float*)d_out);
}

// Round 9
// 1702.059 us; speedup vs baseline: 4.9723x; 1.0770x over previous
//
#include <hip/hip_runtime.h>
#include <cstdint>
#include <cstddef>

#define Mdim 1024
#define Ndim 4096
#define Bdim 16
#define SMax 512
#define K2v  64
#define KKv  32
#define NIT  8
#define PQ   8     // proxy row chunks

// ---------------------------------------------------------------- init
__global__ __launch_bounds__(256) void k_init(const float* __restrict__ Y, float* __restrict__ Rres,
        int* __restrict__ Flags, int* __restrict__ Sold, int* __restrict__ Snew, int* __restrict__ Done){
  int idx = blockIdx.x * 256 + threadIdx.x;
  int total = Bdim * Ndim;
  for (int t = idx; t < total; t += gridDim.x * 256){
    Flags[t] = 0;
    if (t < Bdim * Mdim) Rres[t] = Y[t];
    if (t < Bdim){ Sold[t] = 0; Snew[t] = 0; Done[t] = 0; }
  }
}

// ---------------------------------------------------------------- transpose A[M][N] -> At[N][M]
__global__ __launch_bounds__(256) void k_transpose(const float* __restrict__ A, float* __restrict__ At){
  __shared__ float tile[32][33];
  int j0 = blockIdx.x * 32, i0 = blockIdx.y * 32;
  int tx = threadIdx.x, ty = threadIdx.y;   // 32 x 8
  for (int r = 0; r < 32; r += 8)
    tile[ty + r][tx] = A[(size_t)(i0 + ty + r) * Ndim + (j0 + tx)];
  __syncthreads();
  for (int r = 0; r < 32; r += 8)
    At[(size_t)(j0 + ty + r) * Mdim + (i0 + tx)] = tile[tx][ty + r];
}

// ---------------------------------------------------------------- proxy partials
__global__ __launch_bounds__(256) void k_proxy(const float* __restrict__ A, const float* __restrict__ Rres,
        float* __restrict__ PP){
  int j = blockIdx.x * 256 + threadIdx.x;
  int rq = blockIdx.y;                       // 8 chunks of 128 rows
  __shared__ float Rq[Bdim][128];
  for (int e = threadIdx.x; e < Bdim * 128; e += 256){
    int b = e >> 7, i = e & 127;
    Rq[b][i] = Rres[b * Mdim + rq * 128 + i];
  }
  __syncthreads();
  float acc[Bdim];
  #pragma unroll
  for (int b = 0; b < Bdim; ++b) acc[b] = 0.0f;
  for (int i = 0; i < 128; ++i){
    float a = A[(size_t)(rq * 128 + i) * Ndim + j];
    #pragma unroll
    for (int b = 0; b < Bdim; ++b) acc[b] = fmaf(a, Rq[b][i], acc[b]);
  }
  #pragma unroll
  for (int b = 0; b < Bdim; ++b)
    PP[(size_t)(rq * Bdim + b) * Ndim + j] = acc[b];
}

// ---------------------------------------------------------------- top-64 of |proxy|, update support
__global__ __launch_bounds__(1024) void k_topk(const float* __restrict__ PP, int* __restrict__ Flags,
        int* __restrict__ Cols, int* __restrict__ Sold, int* __restrict__ Snew, const int* __restrict__ Done){
  int b = blockIdx.x;
  if (Done[b]) return;
  __shared__ unsigned long long keys[Ndim];   // 32KB
  int tid = threadIdx.x;
  for (int j = tid; j < Ndim; j += 1024){
    float v = 0.0f;
    #pragma unroll
    for (int q = 0; q < PQ; ++q) v += PP[(size_t)(q * Bdim + b) * Ndim + j];
    unsigned int ab = __float_as_uint(fabsf(v));
    keys[j] = ((unsigned long long)ab << 32) | (unsigned int)j;
  }
  __syncthreads();
  for (int ksz = 2; ksz <= Ndim; ksz <<= 1){
    for (int jsz = ksz >> 1; jsz > 0; jsz >>= 1){
      for (int t = tid; t < Ndim / 2; t += 1024){
        int i = 2 * t - (t & (jsz - 1));
        int ixj = i ^ jsz;
        unsigned long long a = keys[i], c = keys[ixj];
        bool sw = ((i & ksz) == 0) ? (a < c) : (a > c);
        if (sw){ keys[i] = c; keys[ixj] = a; }
      }
      __syncthreads();
    }
  }
  if (tid < 64){
    int s = Snew[b];
    if (tid == 0) Sold[b] = s;
    int j = (int)(keys[tid] & 0xFFFFFFFFu);
    int notin = (Flags[b * Ndim + j] == 0) ? 1 : 0;
    unsigned long long bal = __ballot(notin);
    if (notin){
      int pos = s + __popcll(bal & ((1ull << tid) - 1ull));
      Flags[b * Ndim + j] = 1;
      Cols[b * SMax + pos] = j;
    }
    if (tid == 0) Snew[b] = s + (int)__popcll(bal);
  }
}

// ---------------------------------------------------------------- incremental Gram rows + rhs (q-split over z)
__global__ __launch_bounds__(256) void k_gram(const float* __restrict__ At, const float* __restrict__ Y,
        float* __restrict__ G, float* __restrict__ Bv,
        const int* __restrict__ Cols, const int* __restrict__ Sold, const int* __restrict__ Snew,
        const int* __restrict__ Done){
  int b = blockIdx.x;
  if (Done[b]) return;
  int s0 = Sold[b], s1 = Snew[b];
  int p0 = s0 + (int)blockIdx.y * 4;
  if (p0 >= s1) return;
  int np = min(4, s1 - p0);
  __shared__ float Ap[4][Mdim];   // 16KB
  int tid = threadIdx.x;
  for (int e = tid; e < 4 * Mdim; e += 256){
    int pi = e >> 10, i = e & (Mdim - 1);
    Ap[pi][i] = (p0 + pi < s1) ? At[(size_t)Cols[b * SMax + p0 + pi] * Mdim + i] : 0.0f;
  }
  __syncthreads();
  int w = tid >> 6, lane = tid & 63;
  for (int q = 4 * (int)blockIdx.z + w; q <= s1; q += 8){   // q == s1 => rhs (dot with y)
    const float* aq = (q < s1) ? (At + (size_t)Cols[b * SMax + q] * Mdim) : (Y + (size_t)b * Mdim);
    float a0 = 0, a1 = 0, a2 = 0, a3 = 0;
    #pragma unroll
    for (int c = 0; c < 16; ++c){
      float v = aq[lane + 64 * c];
      a0 = fmaf(v, Ap[0][lane + 64 * c], a0);
      a1 = fmaf(v, Ap[1][lane + 64 * c], a1);
      a2 = fmaf(v, Ap[2][lane + 64 * c], a2);
      a3 = fmaf(v, Ap[3][lane + 64 * c], a3);
    }
    #pragma unroll
    for (int off = 32; off > 0; off >>= 1){
      a0 += __shfl_xor(a0, off);
      a1 += __shfl_xor(a1, off);
      a2 += __shfl_xor(a2, off);
      a3 += __shfl_xor(a3, off);
    }
    if (lane == 0){
      float av[4] = {a0, a1, a2, a3};
      for (int r = 0; r < np; ++r){
        int p = p0 + r;
        if (q < s1){
          G[((size_t)b * SMax + p) * SMax + q] = av[r];
          G[((size_t)b * SMax + q) * SMax + p] = av[r];
        } else {
          Bv[(size_t)b * SMax + p] = av[r];
        }
      }
    }
  }
}

// ---------------------------------------------------------------- V = Gi_old @ B
__global__ __launch_bounds__(256) void k_V(const float* __restrict__ G, const float* __restrict__ Gi,
        float* __restrict__ V, const int* __restrict__ Sold, const int* __restrict__ Snew,
        const int* __restrict__ Done){
  int b = blockIdx.x;
  if (Done[b]) return;
  int s0 = Sold[b], s1 = Snew[b], nn = s1 - s0;
  int i0 = (int)blockIdx.y * 64;
  if (i0 >= s0) return;
  __shared__ float Gt[64][65];
  __shared__ float Bt[64][65];
  int tid = threadIdx.x;
  int tx = tid & 15, ty = tid >> 4;
  float acc[4][4];
  #pragma unroll
  for (int r = 0; r < 4; ++r)
    #pragma unroll
    for (int c = 0; c < 4; ++c) acc[r][c] = 0.0f;
  for (int k0 = 0; k0 < s0; k0 += 64){
    for (int e = tid; e < 64 * 64; e += 256){
      int r = e >> 6, c = e & 63;
      Gt[r][c] = Gi[((size_t)b * SMax + i0 + r) * SMax + k0 + c];
      Bt[r][c] = (k0 + r < s0 && c < nn) ? G[((size_t)b * SMax + k0 + r) * SMax + s0 + c] : 0.0f;
    }
    __syncthreads();
    for (int d = 0; d < 64; ++d){
      float gv[4], bv[4];
      #pragma unroll
      for (int r = 0; r < 4; ++r) gv[r] = Gt[ty * 4 + r][d];
      #pragma unroll
      for (int c = 0; c < 4; ++c) bv[c] = Bt[d][tx * 4 + c];
      #pragma unroll
      for (int r = 0; r < 4; ++r)
        #pragma unroll
        for (int c = 0; c < 4; ++c) acc[r][c] = fmaf(gv[r], bv[c], acc[r][c]);
    }
    __syncthreads();
  }
  for (int r = 0; r < 4; ++r)
    for (int c = 0; c < 4; ++c){
      int i = i0 + ty * 4 + r, cc = tx * 4 + c;
      if (i < s0 && cc < nn)
        V[((size_t)b * SMax + i) * K2v + cc] = acc[r][c];
    }
}

// ---------------------------------------------------------------- wide Schur partial: SP[b][tile] = B(tile)^T V(tile)
__global__ __launch_bounds__(256) void k_S(const float* __restrict__ G, const float* __restrict__ V,
        float* __restrict__ SP, const int* __restrict__ Sold, const int* __restrict__ Snew,
        const int* __restrict__ Done){
  int b = blockIdx.x;
  if (Done[b]) return;
  int s0 = Sold[b], s1 = Snew[b], nn = s1 - s0;
  int k0 = (int)blockIdx.y * 64;
  if (k0 >= s0) return;
  __shared__ float Bt[64][65];
  __shared__ float Vt[64][65];
  int tid = threadIdx.x;
  int tx = tid & 15, ty = tid >> 4;
  for (int e = tid; e < 64 * 64; e += 256){
    int r = e >> 6, c = e & 63;
    bool ok = (k0 + r < s0) && (c < nn);
    Bt[r][c] = ok ? G[((size_t)b * SMax + k0 + r) * SMax + s0 + c] : 0.0f;
    Vt[r][c] = ok ? V[((size_t)b * SMax + k0 + r) * K2v + c] : 0.0f;
  }
  __syncthreads();
  float acc[4][4];
  #pragma unroll
  for (int r = 0; r < 4; ++r)
    #pragma unroll
    for (int c = 0; c < 4; ++c) acc[r][c] = 0.0f;
  for (int d = 0; d < 64; ++d){
    float bm[4], vv[4];
    #pragma unroll
    for (int r = 0; r < 4; ++r) bm[r] = Bt[d][ty * 4 + r];
    #pragma unroll
    for (int c = 0; c < 4; ++c) vv[c] = Vt[d][tx * 4 + c];
    #pragma unroll
    for (int r = 0; r < 4; ++r)
      #pragma unroll
      for (int c = 0; c < 4; ++c) acc[r][c] = fmaf(bm[r], vv[c], acc[r][c]);
  }
  float* dst = SP + ((size_t)(b * 8 + (int)blockIdx.y)) * 4096;
  #pragma unroll
  for (int r = 0; r < 4; ++r)
    #pragma unroll
    for (int c = 0; c < 4; ++c)
      dst[(ty * 4 + r) * 64 + tx * 4 + c] = acc[r][c];
}

// ---------------------------------------------------------------- register-resident 64x64 Gauss-Jordan
template<int J, int I> struct RowU {
  static __device__ __forceinline__ void go(float (&s)[64], float (&w)[64]){
    if constexpr (I != J){
      float f = __uint_as_float((unsigned)__builtin_amdgcn_readlane((int)__float_as_uint(s[I]), J));
      s[I] = fmaf(-f, s[J], s[I]);
      w[I] = fmaf(-f, w[J], w[I]);
    }
    if constexpr (I + 1 < 64) RowU<J, I + 1>::go(s, w);
  }
};
template<int J> struct PivT {
  static __device__ __forceinline__ void go(float (&s)[64], float (&w)[64]){
    float d = __uint_as_float((unsigned)__builtin_amdgcn_readlane((int)__float_as_uint(s[J]), J));
    float rp = 1.0f / d;
    s[J] *= rp;
    w[J] *= rp;
    RowU<J, 0>::go(s, w);
    if constexpr (J + 1 < 64) PivT<J + 1>::go(s, w);
  }
};

// ---------------------------------------------------------------- Sm = Gnn - sum(SP); Si = Sm^{-1}
__global__ __launch_bounds__(256, 1) void k_schur(const float* __restrict__ G, const float* __restrict__ SP,
        float* __restrict__ Si, const int* __restrict__ Sold, const int* __restrict__ Snew,
        const int* __restrict__ Done){
  int b = blockIdx.x;
  if (Done[b]) return;
  int s0 = Sold[b], s1 = Snew[b], nn = s1 - s0;
  int ntiles = (s0 + 63) >> 6;
  __shared__ float Sm[64][65];
  int tid = threadIdx.x;
  for (int e = tid; e < 4096; e += 256){
    int rr = e >> 6, cc = e & 63;
    float sval;
    if (rr < nn && cc < nn){
      sval = G[((size_t)b * SMax + s0 + rr) * SMax + s0 + cc];
      for (int t = 0; t < ntiles; ++t)
        sval -= SP[((size_t)(b * 8 + t)) * 4096 + e];
    } else {
      sval = (rr == cc) ? 1.0f : 0.0f;
    }
    Sm[rr][cc] = sval;
  }
  __syncthreads();
  // single-wave register GJ: lane = column; zero barriers, zero LDS traffic
  if (tid < 64){
    float s[64], w[64];
    #pragma unroll
    for (int r = 0; r < 64; ++r){
      s[r] = Sm[r][tid];
      w[r] = (r == tid) ? 1.0f : 0.0f;
    }
    PivT<0>::go(s, w);
    #pragma unroll
    for (int r = 0; r < 64; ++r)
      Si[(size_t)b * K2v * K2v + r * K2v + tid] = w[r];
  }
}

// ---------------------------------------------------------------- T = V @ Si
__global__ __launch_bounds__(256) void k_T(const float* __restrict__ V, const float* __restrict__ Si,
        float* __restrict__ T, const int* __restrict__ Sold, const int* __restrict__ Snew,
        const int* __restrict__ Done){
  int b = blockIdx.x;
  if (Done[b]) return;
  int s0 = Sold[b], s1 = Snew[b], nn = s1 - s0;
  int i0 = (int)blockIdx.y * 64;
  if (i0 >= s0) return;
  __shared__ float Vt[64][65];
  __shared__ float Ss[64][65];
  int tid = threadIdx.x;
  for (int e = tid; e < 64 * 64; e += 256){
    int r = e >> 6, c = e & 63;
    Vt[r][c] = (i0 + r < s0 && c < nn) ? V[((size_t)b * SMax + i0 + r) * K2v + c] : 0.0f;
    Ss[r][c] = Si[(size_t)b * K2v * K2v + e];
  }
  __syncthreads();
  int tx = tid & 15, ty = tid >> 4;
  float acc[4][4];
  #pragma unroll
  for (int r = 0; r < 4; ++r)
    #pragma unroll
    for (int c = 0; c < 4; ++c) acc[r][c] = 0.0f;
  for (int d = 0; d < 64; ++d){
    float vv[4], sv[4];
    #pragma unroll
    for (int r = 0; r < 4; ++r) vv[r] = Vt[ty * 4 + r][d];
    #pragma unroll
    for (int c = 0; c < 4; ++c) sv[c] = Ss[d][tx * 4 + c];
    #pragma unroll
    for (int r = 0; r < 4; ++r)
      #pragma unroll
      for (int c = 0; c < 4; ++c) acc[r][c] = fmaf(vv[r], sv[c], acc[r][c]);
  }
  for (int r = 0; r < 4; ++r)
    for (int c = 0; c < 4; ++c){
      int i = i0 + ty * 4 + r, dd = tx * 4 + c;
      if (i < s0 && dd < nn)
        T[((size_t)b * SMax + i) * K2v + dd] = acc[r][c];
    }
}

// ---------------------------------------------------------------- Gi <- bordered inverse update (in place)
__global__ __launch_bounds__(256) void k_upd(float* __restrict__ Gi, const float* __restrict__ T,
        const float* __restrict__ V, const float* __restrict__ Si,
        const int* __restrict__ Sold, const int* __restrict__ Snew, const int* __restrict__ Done){
  int b = blockIdx.x;
  if (Done[b]) return;
  int s0 = Sold[b], s1 = Snew[b];
  int i0 = (int)blockIdx.y * 64, k0 = (int)blockIdx.z * 64;
  if (i0 >= s1 || k0 >= s1) return;
  int nn = s1 - s0;
  __shared__ float Tt[64][65];
  __shared__ float Vk[64][65];
  __shared__ float Tk[64][65];
  int tid = threadIdx.x;
  for (int e = tid; e < 64 * 64; e += 256){
    int r = e >> 6, c = e & 63;
    Tt[r][c] = (i0 + r < s0 && c < nn) ? T[((size_t)b * SMax + i0 + r) * K2v + c] : 0.0f;
    Tk[r][c] = (k0 + r < s0 && c < nn) ? T[((size_t)b * SMax + k0 + r) * K2v + c] : 0.0f;
    Vk[r][c] = (k0 + r < s0 && c < nn) ? V[((size_t)b * SMax + k0 + r) * K2v + c] : 0.0f;
  }
  __syncthreads();
  int tx = tid & 15, ty = tid >> 4;
  float acc[4][4];
  #pragma unroll
  for (int r = 0; r < 4; ++r)
    #pragma unroll
    for (int c = 0; c < 4; ++c) acc[r][c] = 0.0f;
  for (int d = 0; d < 64; ++d){
    float tv[4], vv[4];
    #pragma unroll
    for (int r = 0; r < 4; ++r) tv[r] = Tt[ty * 4 + r][d];
    #pragma unroll
    for (int c = 0; c < 4; ++c) vv[c] = Vk[tx * 4 + c][d];
    #pragma unroll
    for (int r = 0; r < 4; ++r)
      #pragma unroll
      for (int c = 0; c < 4; ++c) acc[r][c] = fmaf(tv[r], vv[c], acc[r][c]);
  }
  for (int r = 0; r < 4; ++r)
    for (int c = 0; c < 4; ++c){
      int i = i0 + ty * 4 + r, k = k0 + tx * 4 + c;
      if (i < s1 && k < s1){
        size_t idx = ((size_t)b * SMax + i) * SMax + k;
        float val;
        if (i < s0){
          if (k < s0) val = Gi[idx] + acc[r][c];
          else        val = -Tt[ty * 4 + r][k - s0];
        } else {
          if (k < s0) val = -Tk[tx * 4 + c][i - s0];
          else        val = Si[(size_t)b * K2v * K2v + (i - s0) * K2v + (k - s0)];
        }
        Gi[idx] = val;
      }
    }
}

// ---------------------------------------------------------------- wide GEMV: out = sgn*(Mat@vec) + add
__global__ __launch_bounds__(256) void k_gemv(const float* __restrict__ Mat, const float* __restrict__ vecsrc,
        const float* __restrict__ addsrc, float* __restrict__ out, float sgn,
        const int* __restrict__ Snew, const int* __restrict__ Done){
  int b = blockIdx.x;
  if (Done[b]) return;
  int s1 = Snew[b];
  int i0 = (int)blockIdx.y * 64;
  if (i0 >= s1) return;
  __shared__ float vs[SMax];
  int tid = threadIdx.x;
  int w = tid >> 6, lane = tid & 63;
  vs[tid]       = (tid < s1)       ? vecsrc[(size_t)b * SMax + tid]       : 0.0f;
  vs[tid + 256] = (tid + 256 < s1) ? vecsrc[(size_t)b * SMax + tid + 256] : 0.0f;
  __syncthreads();
  #pragma unroll
  for (int g = 0; g < 4; ++g){
    int base = i0 + w * 16 + g * 4;         // 4 consecutive rows
    if (base >= s1) break;
    const float* p0 = Mat + ((size_t)b * SMax + base) * SMax;
    const float* p1 = Mat + ((size_t)b * SMax + (base + 1 < s1 ? base + 1 : base)) * SMax;
    const float* p2 = Mat + ((size_t)b * SMax + (base + 2 < s1 ? base + 2 : base)) * SMax;
    const float* p3 = Mat + ((size_t)b * SMax + (base + 3 < s1 ? base + 3 : base)) * SMax;
    float a0 = 0, a1 = 0, a2 = 0, a3 = 0;
    #pragma unroll
    for (int c = 0; c < 8; ++c){
      int idx = lane + 64 * c;
      float v = vs[idx];
      a0 = fmaf(p0[idx], v, a0);
      a1 = fmaf(p1[idx], v, a1);
      a2 = fmaf(p2[idx], v, a2);
      a3 = fmaf(p3[idx], v, a3);
    }
    #pragma unroll
    for (int off = 32; off > 0; off >>= 1){
      a0 += __shfl_xor(a0, off); a1 += __shfl_xor(a1, off);
      a2 += __shfl_xor(a2, off); a3 += __shfl_xor(a3, off);
    }
    if (lane == 0){
      float av[4] = {a0, a1, a2, a3};
      #pragma unroll
      for (int r = 0; r < 4; ++r){
        int i = base + r;
        if (i < s1)
          out[(size_t)b * SMax + i] = sgn * av[r] + (addsrc ? addsrc[(size_t)b * SMax + i] : 0.0f);
      }
    }
  }
}

// ---------------------------------------------------------------- top-32 threshold, new residual, convergence
__global__ __launch_bounds__(1024) void k_finish(const float* __restrict__ Zz, const float* __restrict__ At,
        const float* __restrict__ Y, const int* __restrict__ Cols, const int* __restrict__ Snew,
        int* __restrict__ Done, float* __restrict__ XKval, int* __restrict__ XKcol, float* __restrict__ Rres){
  int b = blockIdx.x;
  if (Done[b]) return;
  int s1 = Snew[b];
  __shared__ unsigned long long sk[SMax];
  __shared__ float xv[KKv];
  __shared__ int   xc[KKv];
  __shared__ float red[16];
  int tid = threadIdx.x;
  if (tid < SMax){
    unsigned long long key = 0;
    if (tid < s1){
      float z = Zz[(size_t)b * SMax + tid];
      unsigned int ab = __float_as_uint(fabsf(z));
      int col = Cols[b * SMax + tid];
      key = ((unsigned long long)ab << 32) | ((unsigned long long)(4095 - col) << 20) | (unsigned int)tid;
    }
    sk[tid] = key;
  }
  __syncthreads();
  for (int ksz = 2; ksz <= SMax; ksz <<= 1){
    for (int jsz = ksz >> 1; jsz > 0; jsz >>= 1){
      for (int t = tid; t < SMax / 2; t += 1024){
        int i = 2 * t - (t & (jsz - 1));
        int ixj = i ^ jsz;
        unsigned long long a = sk[i], c = sk[ixj];
        bool sw = ((i & ksz) == 0) ? (a < c) : (a > c);
        if (sw){ sk[i] = c; sk[ixj] = a; }
      }
      __syncthreads();
    }
  }
  if (tid < KKv){
    unsigned long long key = sk[tid];
    int p = (int)(key & 0xFFFFFu);
    float v = Zz[(size_t)b * SMax + p];
    xv[tid] = v;
    xc[tid] = Cols[b * SMax + p];
    XKval[b * KKv + tid] = v;
    XKcol[b * KKv + tid] = xc[tid];
  }
  __syncthreads();
  float r = Y[(size_t)b * Mdim + tid];
  for (int t = 0; t < KKv; ++t)
    r = fmaf(-xv[t], At[(size_t)xc[t] * Mdim + tid], r);
  Rres[(size_t)b * Mdim + tid] = r;
  float ss = r * r;
  #pragma unroll
  for (int off = 32; off > 0; off >>= 1) ss += __shfl_xor(ss, off);
  if ((tid & 63) == 0) red[tid >> 6] = ss;
  __syncthreads();
  if (tid == 0){
    float tot = 0;
    for (int w = 0; w < 16; ++w) tot += red[w];
    if (tot < 1e-12f) Done[b] = 1;
  }
}

// ---------------------------------------------------------------- dense output
__global__ __launch_bounds__(1024) void k_output(const float* __restrict__ XKval, const int* __restrict__ XKcol,
        float* __restrict__ out){
  int b = blockIdx.x;
  __shared__ float xv[KKv];
  __shared__ int   xc[KKv];
  if (threadIdx.x < KKv){
    xv[threadIdx.x] = XKval[b * KKv + threadIdx.x];
    xc[threadIdx.x] = XKcol[b * KKv + threadIdx.x];
  }
  __syncthreads();
  int j = blockIdx.y * 1024 + threadIdx.x;
  float v = 0.0f;
  #pragma unroll
  for (int t = 0; t < KKv; ++t) v = (xc[t] == j) ? xv[t] : v;
  out[(size_t)b * Ndim + j] = v;
}

// ----------------------------------------------------------------
extern "C" void kernel_launch(void* const* d_in, const int* in_sizes, int n_in,
                              void* d_out, int out_size, void* d_ws, size_t ws_size,
                              hipStream_t stream){
  const float* Y = (const float*)d_in[0];   // [B][M]
  const float* A = (const float*)d_in[1];   // [M][N]
  float* ws = (float*)d_ws;
  size_t off = 0;
  float* At   = ws + off; off += (size_t)Ndim * Mdim;
  float* G    = ws + off; off += (size_t)Bdim * SMax * SMax;
  float* Gi   = ws + off; off += (size_t)Bdim * SMax * SMax;
  float* V    = ws + off; off += (size_t)Bdim * SMax * K2v;
  float* T    = ws + off; off += (size_t)Bdim * SMax * K2v;
  float* Si   = ws + off; off += (size_t)Bdim * K2v * K2v;
  float* PP   = ws + off; off += (size_t)PQ * Bdim * Ndim;   // also reused as SP (Schur partials)
  float* Rres = ws + off; off += (size_t)Bdim * Mdim;
  float* Bv   = ws + off; off += (size_t)Bdim * SMax;
  float* Z0   = ws + off; off += (size_t)Bdim * SMax;
  float* R2   = ws + off; off += (size_t)Bdim * SMax;
  float* Zz   = ws + off; off += (size_t)Bdim * SMax;
  float* XKval = ws + off; off += (size_t)Bdim * KKv;
  int* XKcol = (int*)(ws + off); off += (size_t)Bdim * KKv;
  int* Cols  = (int*)(ws + off); off += (size_t)Bdim * SMax;
  int* Flags = (int*)(ws + off); off += (size_t)Bdim * Ndim;
  int* Sold  = (int*)(ws + off); off += Bdim;
  int* Snew  = (int*)(ws + off); off += Bdim;
  int* Done  = (int*)(ws + off); off += Bdim;
  float* SP = PP;   // PP is dead between topk(t) and proxy(t+1) -> reuse as Schur partials

  k_init<<<256, 256, 0, stream>>>(Y, Rres, Flags, Sold, Snew, Done);
  k_transpose<<<dim3(Ndim / 32, Mdim / 32), dim3(32, 8), 0, stream>>>(A, At);
  for (int t = 0; t < NIT; ++t){
    k_proxy<<<dim3(Ndim / 256, PQ), 256, 0, stream>>>(A, Rres, PP);
    k_topk<<<Bdim, 1024, 0, stream>>>(PP, Flags, Cols, Sold, Snew, Done);
    k_gram<<<dim3(Bdim, 16, 2), 256, 0, stream>>>(At, Y, G, Bv, Cols, Sold, Snew, Done);
    if (t > 0){
      k_V<<<dim3(Bdim, t), 256, 0, stream>>>(G, Gi, V, Sold, Snew, Done);
      k_S<<<dim3(Bdim, t), 256, 0, stream>>>(G, V, SP, Sold, Snew, Done);
    }
    k_schur<<<Bdim, 256, 0, stream>>>(G, SP, Si, Sold, Snew, Done);
    if (t > 0)
      k_T<<<dim3(Bdim, t), 256, 0, stream>>>(V, Si, T, Sold, Snew, Done);
    k_upd<<<dim3(Bdim, t + 1, t + 1), 256, 0, stream>>>(Gi, T, V, Si, Sold, Snew, Done);
    k_gemv<<<dim3(Bdim, 8), 256, 0, stream>>>(Gi, Bv, nullptr, Z0, 1.0f, Snew, Done);
    k_gemv<<<dim3(Bdim, 8), 256, 0, stream>>>(G, Z0, Bv, R2, -1.0f, Snew, Done);
    k_gemv<<<dim3(Bdim, 8), 256, 0, stream>>>(Gi, R2, Z0, Zz, 1.0f, Snew, Done);
    k_finish<<<Bdim, 1024, 0, stream>>>(Zz, At, Y, Cols, Snew, Done, XKval, XKcol, Rres);
  }
  k_output<<<dim3(Bdim, Ndim / 1024), 1024, 0, stream>>>(XKval, XKcol, (float*)d_out);
}

// Round 10
// 1646.043 us; speedup vs baseline: 5.1415x; 1.0340x over previous
//
#include <hip/hip_runtime.h>
#include <cstdint>
#include <cstddef>

#define Mdim 1024
#define Ndim 4096
#define Bdim 16
#define SMax 512
#define K2v  64
#define KKv  32
#define NIT  8
#define PQ   8     // proxy row chunks

// ---------------------------------------------------------------- init
__global__ __launch_bounds__(256) void k_init(const float* __restrict__ Y, float* __restrict__ Rres,
        int* __restrict__ Flags, int* __restrict__ Sold, int* __restrict__ Snew, int* __restrict__ Done){
  int idx = blockIdx.x * 256 + threadIdx.x;
  int total = Bdim * Ndim;
  for (int t = idx; t < total; t += gridDim.x * 256){
    Flags[t] = 0;
    if (t < Bdim * Mdim) Rres[t] = Y[t];
    if (t < Bdim){ Sold[t] = 0; Snew[t] = 0; Done[t] = 0; }
  }
}

// ---------------------------------------------------------------- transpose A[M][N] -> At[N][M]
__global__ __launch_bounds__(256) void k_transpose(const float* __restrict__ A, float* __restrict__ At){
  __shared__ float tile[32][33];
  int j0 = blockIdx.x * 32, i0 = blockIdx.y * 32;
  int tx = threadIdx.x, ty = threadIdx.y;   // 32 x 8
  for (int r = 0; r < 32; r += 8)
    tile[ty + r][tx] = A[(size_t)(i0 + ty + r) * Ndim + (j0 + tx)];
  __syncthreads();
  for (int r = 0; r < 32; r += 8)
    At[(size_t)(j0 + ty + r) * Mdim + (i0 + tx)] = tile[tx][ty + r];
}

// ---------------------------------------------------------------- proxy partials
__global__ __launch_bounds__(256) void k_proxy(const float* __restrict__ A, const float* __restrict__ Rres,
        float* __restrict__ PP){
  int j = blockIdx.x * 256 + threadIdx.x;
  int rq = blockIdx.y;                       // 8 chunks of 128 rows
  __shared__ float Rq[Bdim][128];
  for (int e = threadIdx.x; e < Bdim * 128; e += 256){
    int b = e >> 7, i = e & 127;
    Rq[b][i] = Rres[b * Mdim + rq * 128 + i];
  }
  __syncthreads();
  float acc[Bdim];
  #pragma unroll
  for (int b = 0; b < Bdim; ++b) acc[b] = 0.0f;
  for (int i = 0; i < 128; ++i){
    float a = A[(size_t)(rq * 128 + i) * Ndim + j];
    #pragma unroll
    for (int b = 0; b < Bdim; ++b) acc[b] = fmaf(a, Rq[b][i], acc[b]);
  }
  #pragma unroll
  for (int b = 0; b < Bdim; ++b)
    PP[(size_t)(rq * Bdim + b) * Ndim + j] = acc[b];
}

// ---------------------------------------------------------------- top-64 of |proxy|, update support
__global__ __launch_bounds__(1024) void k_topk(const float* __restrict__ PP, int* __restrict__ Flags,
        int* __restrict__ Cols, int* __restrict__ Sold, int* __restrict__ Snew, const int* __restrict__ Done){
  int b = blockIdx.x;
  if (Done[b]) return;
  __shared__ unsigned long long keys[Ndim];   // 32KB
  int tid = threadIdx.x;
  for (int j = tid; j < Ndim; j += 1024){
    float v = 0.0f;
    #pragma unroll
    for (int q = 0; q < PQ; ++q) v += PP[(size_t)(q * Bdim + b) * Ndim + j];
    unsigned int ab = __float_as_uint(fabsf(v));
    keys[j] = ((unsigned long long)ab << 32) | (unsigned int)j;
  }
  __syncthreads();
  for (int ksz = 2; ksz <= Ndim; ksz <<= 1){
    for (int jsz = ksz >> 1; jsz > 0; jsz >>= 1){
      for (int t = tid; t < Ndim / 2; t += 1024){
        int i = 2 * t - (t & (jsz - 1));
        int ixj = i ^ jsz;
        unsigned long long a = keys[i], c = keys[ixj];
        bool sw = ((i & ksz) == 0) ? (a < c) : (a > c);
        if (sw){ keys[i] = c; keys[ixj] = a; }
      }
      __syncthreads();
    }
  }
  if (tid < 64){
    int s = Snew[b];
    if (tid == 0) Sold[b] = s;
    int j = (int)(keys[tid] & 0xFFFFFFFFu);
    int notin = (Flags[b * Ndim + j] == 0) ? 1 : 0;
    unsigned long long bal = __ballot(notin);
    if (notin){
      int pos = s + __popcll(bal & ((1ull << tid) - 1ull));
      Flags[b * Ndim + j] = 1;
      Cols[b * SMax + pos] = j;
    }
    if (tid == 0) Snew[b] = s + (int)__popcll(bal);
  }
}

// ---------------------------------------------------------------- incremental Gram rows + rhs (q-split over z)
__global__ __launch_bounds__(256) void k_gram(const float* __restrict__ At, const float* __restrict__ Y,
        float* __restrict__ G, float* __restrict__ Bv,
        const int* __restrict__ Cols, const int* __restrict__ Sold, const int* __restrict__ Snew,
        const int* __restrict__ Done){
  int b = blockIdx.x;
  if (Done[b]) return;
  int s0 = Sold[b], s1 = Snew[b];
  int p0 = s0 + (int)blockIdx.y * 4;
  if (p0 >= s1) return;
  int np = min(4, s1 - p0);
  __shared__ float Ap[4][Mdim];   // 16KB
  int tid = threadIdx.x;
  for (int e = tid; e < 4 * Mdim; e += 256){
    int pi = e >> 10, i = e & (Mdim - 1);
    Ap[pi][i] = (p0 + pi < s1) ? At[(size_t)Cols[b * SMax + p0 + pi] * Mdim + i] : 0.0f;
  }
  __syncthreads();
  int w = tid >> 6, lane = tid & 63;
  for (int q = 4 * (int)blockIdx.z + w; q <= s1; q += 8){   // q == s1 => rhs (dot with y)
    const float* aq = (q < s1) ? (At + (size_t)Cols[b * SMax + q] * Mdim) : (Y + (size_t)b * Mdim);
    float a0 = 0, a1 = 0, a2 = 0, a3 = 0;
    #pragma unroll
    for (int c = 0; c < 16; ++c){
      float v = aq[lane + 64 * c];
      a0 = fmaf(v, Ap[0][lane + 64 * c], a0);
      a1 = fmaf(v, Ap[1][lane + 64 * c], a1);
      a2 = fmaf(v, Ap[2][lane + 64 * c], a2);
      a3 = fmaf(v, Ap[3][lane + 64 * c], a3);
    }
    #pragma unroll
    for (int off = 32; off > 0; off >>= 1){
      a0 += __shfl_xor(a0, off);
      a1 += __shfl_xor(a1, off);
      a2 += __shfl_xor(a2, off);
      a3 += __shfl_xor(a3, off);
    }
    if (lane == 0){
      float av[4] = {a0, a1, a2, a3};
      for (int r = 0; r < np; ++r){
        int p = p0 + r;
        if (q < s1){
          G[((size_t)b * SMax + p) * SMax + q] = av[r];
          G[((size_t)b * SMax + q) * SMax + p] = av[r];
        } else {
          Bv[(size_t)b * SMax + p] = av[r];
        }
      }
    }
  }
}

// ---------------------------------------------------------------- V = Gi_old @ B, fused Schur partial SP = B(i0)^T V(i0)
__global__ __launch_bounds__(256) void k_V(const float* __restrict__ G, const float* __restrict__ Gi,
        float* __restrict__ V, float* __restrict__ SP,
        const int* __restrict__ Sold, const int* __restrict__ Snew, const int* __restrict__ Done){
  int b = blockIdx.x;
  if (Done[b]) return;
  int s0 = Sold[b], s1 = Snew[b], nn = s1 - s0;
  int i0 = (int)blockIdx.y * 64;
  if (i0 >= s0) return;
  __shared__ float Gt[64][65];
  __shared__ float Bt[64][65];
  int tid = threadIdx.x;
  int tx = tid & 15, ty = tid >> 4;
  float acc[4][4];
  #pragma unroll
  for (int r = 0; r < 4; ++r)
    #pragma unroll
    for (int c = 0; c < 4; ++c) acc[r][c] = 0.0f;
  for (int k0 = 0; k0 < s0; k0 += 64){
    for (int e = tid; e < 64 * 64; e += 256){
      int r = e >> 6, c = e & 63;
      Gt[r][c] = Gi[((size_t)b * SMax + i0 + r) * SMax + k0 + c];
      Bt[r][c] = (k0 + r < s0 && c < nn) ? G[((size_t)b * SMax + k0 + r) * SMax + s0 + c] : 0.0f;
    }
    __syncthreads();
    for (int d = 0; d < 64; ++d){
      float gv[4], bv[4];
      #pragma unroll
      for (int r = 0; r < 4; ++r) gv[r] = Gt[ty * 4 + r][d];
      #pragma unroll
      for (int c = 0; c < 4; ++c) bv[c] = Bt[d][tx * 4 + c];
      #pragma unroll
      for (int r = 0; r < 4; ++r)
        #pragma unroll
        for (int c = 0; c < 4; ++c) acc[r][c] = fmaf(gv[r], bv[c], acc[r][c]);
    }
    __syncthreads();
  }
  // write V tile + park it in LDS (Gt reused as Vt)
  for (int r = 0; r < 4; ++r)
    for (int c = 0; c < 4; ++c){
      int i = i0 + ty * 4 + r, cc = tx * 4 + c;
      float v = acc[r][c];
      Gt[ty * 4 + r][tx * 4 + c] = (i < s0 && cc < nn) ? v : 0.0f;
      if (i < s0 && cc < nn)
        V[((size_t)b * SMax + i) * K2v + cc] = v;
    }
  // restage B rows i0..i0+63 and compute SP[b][i0/64] = B(i0)^T V(i0)
  for (int e = tid; e < 64 * 64; e += 256){
    int r = e >> 6, c = e & 63;
    Bt[r][c] = (i0 + r < s0 && c < nn) ? G[((size_t)b * SMax + i0 + r) * SMax + s0 + c] : 0.0f;
  }
  __syncthreads();
  float sacc[4][4];
  #pragma unroll
  for (int r = 0; r < 4; ++r)
    #pragma unroll
    for (int c = 0; c < 4; ++c) sacc[r][c] = 0.0f;
  for (int d = 0; d < 64; ++d){
    float bm[4], vv[4];
    #pragma unroll
    for (int r = 0; r < 4; ++r) bm[r] = Bt[d][ty * 4 + r];
    #pragma unroll
    for (int c = 0; c < 4; ++c) vv[c] = Gt[d][tx * 4 + c];
    #pragma unroll
    for (int r = 0; r < 4; ++r)
      #pragma unroll
      for (int c = 0; c < 4; ++c) sacc[r][c] = fmaf(bm[r], vv[c], sacc[r][c]);
  }
  float* dst = SP + ((size_t)(b * 8 + (int)blockIdx.y)) * 4096;
  #pragma unroll
  for (int r = 0; r < 4; ++r)
    #pragma unroll
    for (int c = 0; c < 4; ++c)
      dst[(ty * 4 + r) * 64 + tx * 4 + c] = sacc[r][c];
}

// ---------------------------------------------------------------- register-resident 64x64 Gauss-Jordan
template<int J, int I> struct RowU {
  static __device__ __forceinline__ void go(float (&s)[64], float (&w)[64]){
    if constexpr (I != J){
      float f = __uint_as_float((unsigned)__builtin_amdgcn_readlane((int)__float_as_uint(s[I]), J));
      s[I] = fmaf(-f, s[J], s[I]);
      w[I] = fmaf(-f, w[J], w[I]);
    }
    if constexpr (I + 1 < 64) RowU<J, I + 1>::go(s, w);
  }
};
template<int J> struct PivT {
  static __device__ __forceinline__ void go(float (&s)[64], float (&w)[64]){
    float d = __uint_as_float((unsigned)__builtin_amdgcn_readlane((int)__float_as_uint(s[J]), J));
    float rp = __builtin_amdgcn_rcpf(d);   // 1-ulp approx; absorbed by refinement in solve
    s[J] *= rp;
    w[J] *= rp;
    RowU<J, 0>::go(s, w);
    if constexpr (J + 1 < 64) PivT<J + 1>::go(s, w);
  }
};

// ---------------------------------------------------------------- Sm = Gnn - sum(SP); Si = Sm^{-1}
__global__ __launch_bounds__(256, 1) void k_schur(const float* __restrict__ G, const float* __restrict__ SP,
        float* __restrict__ Si, const int* __restrict__ Sold, const int* __restrict__ Snew,
        const int* __restrict__ Done){
  int b = blockIdx.x;
  if (Done[b]) return;
  int s0 = Sold[b], s1 = Snew[b], nn = s1 - s0;
  int ntiles = (s0 + 63) >> 6;
  __shared__ float Sm[64][65];
  int tid = threadIdx.x;
  // each thread: 4 groups of float4 (16 elements); independent per-tile streams
  {
    const float4* sp4 = (const float4*)(SP + (size_t)b * 8 * 4096);
    #pragma unroll
    for (int g = 0; g < 4; ++g){
      int e = tid * 4 + g * 1024;          // float4 index base*4 = element e..e+3
      int rr = e >> 6, cc = e & 63;
      float acc0 = 0, acc1 = 0, acc2 = 0, acc3 = 0;
      for (int t = 0; t < ntiles; ++t){
        float4 v = sp4[t * 1024 + (e >> 2)];
        acc0 += v.x; acc1 += v.y; acc2 += v.z; acc3 += v.w;
      }
      const float* grow = G + ((size_t)b * SMax + s0 + rr) * SMax + s0 + cc;
      #pragma unroll
      for (int q = 0; q < 4; ++q){
        float a = (q == 0) ? acc0 : (q == 1) ? acc1 : (q == 2) ? acc2 : acc3;
        int c = cc + q;
        float sval;
        if (rr < nn && c < nn) sval = grow[q] - a;
        else                   sval = (rr == c) ? 1.0f : 0.0f;
        Sm[rr][c] = sval;
      }
    }
  }
  __syncthreads();
  // single-wave register GJ: lane = column; zero barriers, zero LDS traffic
  if (tid < 64){
    float s[64], w[64];
    #pragma unroll
    for (int r = 0; r < 64; ++r){
      s[r] = Sm[r][tid];
      w[r] = (r == tid) ? 1.0f : 0.0f;
    }
    PivT<0>::go(s, w);
    #pragma unroll
    for (int r = 0; r < 64; ++r)
      Si[(size_t)b * K2v * K2v + r * K2v + tid] = w[r];
  }
}

// ---------------------------------------------------------------- T = V @ Si
__global__ __launch_bounds__(256) void k_T(const float* __restrict__ V, const float* __restrict__ Si,
        float* __restrict__ T, const int* __restrict__ Sold, const int* __restrict__ Snew,
        const int* __restrict__ Done){
  int b = blockIdx.x;
  if (Done[b]) return;
  int s0 = Sold[b], s1 = Snew[b], nn = s1 - s0;
  int i0 = (int)blockIdx.y * 64;
  if (i0 >= s0) return;
  __shared__ float Vt[64][65];
  __shared__ float Ss[64][65];
  int tid = threadIdx.x;
  for (int e = tid; e < 64 * 64; e += 256){
    int r = e >> 6, c = e & 63;
    Vt[r][c] = (i0 + r < s0 && c < nn) ? V[((size_t)b * SMax + i0 + r) * K2v + c] : 0.0f;
    Ss[r][c] = Si[(size_t)b * K2v * K2v + e];
  }
  __syncthreads();
  int tx = tid & 15, ty = tid >> 4;
  float acc[4][4];
  #pragma unroll
  for (int r = 0; r < 4; ++r)
    #pragma unroll
    for (int c = 0; c < 4; ++c) acc[r][c] = 0.0f;
  for (int d = 0; d < 64; ++d){
    float vv[4], sv[4];
    #pragma unroll
    for (int r = 0; r < 4; ++r) vv[r] = Vt[ty * 4 + r][d];
    #pragma unroll
    for (int c = 0; c < 4; ++c) sv[c] = Ss[d][tx * 4 + c];
    #pragma unroll
    for (int r = 0; r < 4; ++r)
      #pragma unroll
      for (int c = 0; c < 4; ++c) acc[r][c] = fmaf(vv[r], sv[c], acc[r][c]);
  }
  for (int r = 0; r < 4; ++r)
    for (int c = 0; c < 4; ++c){
      int i = i0 + ty * 4 + r, dd = tx * 4 + c;
      if (i < s0 && dd < nn)
        T[((size_t)b * SMax + i) * K2v + dd] = acc[r][c];
    }
}

// ---------------------------------------------------------------- Gi <- bordered inverse update (in place)
__global__ __launch_bounds__(256) void k_upd(float* __restrict__ Gi, const float* __restrict__ T,
        const float* __restrict__ V, const float* __restrict__ Si,
        const int* __restrict__ Sold, const int* __restrict__ Snew, const int* __restrict__ Done){
  int b = blockIdx.x;
  if (Done[b]) return;
  int s0 = Sold[b], s1 = Snew[b];
  int i0 = (int)blockIdx.y * 64, k0 = (int)blockIdx.z * 64;
  if (i0 >= s1 || k0 >= s1) return;
  int nn = s1 - s0;
  __shared__ float Tt[64][65];
  __shared__ float Vk[64][65];
  __shared__ float Tk[64][65];
  int tid = threadIdx.x;
  for (int e = tid; e < 64 * 64; e += 256){
    int r = e >> 6, c = e & 63;
    Tt[r][c] = (i0 + r < s0 && c < nn) ? T[((size_t)b * SMax + i0 + r) * K2v + c] : 0.0f;
    Tk[r][c] = (k0 + r < s0 && c < nn) ? T[((size_t)b * SMax + k0 + r) * K2v + c] : 0.0f;
    Vk[r][c] = (k0 + r < s0 && c < nn) ? V[((size_t)b * SMax + k0 + r) * K2v + c] : 0.0f;
  }
  __syncthreads();
  int tx = tid & 15, ty = tid >> 4;
  float acc[4][4];
  #pragma unroll
  for (int r = 0; r < 4; ++r)
    #pragma unroll
    for (int c = 0; c < 4; ++c) acc[r][c] = 0.0f;
  for (int d = 0; d < 64; ++d){
    float tv[4], vv[4];
    #pragma unroll
    for (int r = 0; r < 4; ++r) tv[r] = Tt[ty * 4 + r][d];
    #pragma unroll
    for (int c = 0; c < 4; ++c) vv[c] = Vk[tx * 4 + c][d];
    #pragma unroll
    for (int r = 0; r < 4; ++r)
      #pragma unroll
      for (int c = 0; c < 4; ++c) acc[r][c] = fmaf(tv[r], vv[c], acc[r][c]);
  }
  for (int r = 0; r < 4; ++r)
    for (int c = 0; c < 4; ++c){
      int i = i0 + ty * 4 + r, k = k0 + tx * 4 + c;
      if (i < s1 && k < s1){
        size_t idx = ((size_t)b * SMax + i) * SMax + k;
        float val;
        if (i < s0){
          if (k < s0) val = Gi[idx] + acc[r][c];
          else        val = -Tt[ty * 4 + r][k - s0];
        } else {
          if (k < s0) val = -Tk[tx * 4 + c][i - s0];
          else        val = Si[(size_t)b * K2v * K2v + (i - s0) * K2v + (k - s0)];
        }
        Gi[idx] = val;
      }
    }
}

// ---------------------------------------------------------------- wide GEMV: out = sgn*(Mat@vec) + add
__global__ __launch_bounds__(256) void k_gemv(const float* __restrict__ Mat, const float* __restrict__ vecsrc,
        const float* __restrict__ addsrc, float* __restrict__ out, float sgn,
        const int* __restrict__ Snew, const int* __restrict__ Done){
  int b = blockIdx.x;
  if (Done[b]) return;
  int s1 = Snew[b];
  int i0 = (int)blockIdx.y * 64;
  if (i0 >= s1) return;
  __shared__ float vs[SMax];
  int tid = threadIdx.x;
  int w = tid >> 6, lane = tid & 63;
  vs[tid]       = (tid < s1)       ? vecsrc[(size_t)b * SMax + tid]       : 0.0f;
  vs[tid + 256] = (tid + 256 < s1) ? vecsrc[(size_t)b * SMax + tid + 256] : 0.0f;
  __syncthreads();
  #pragma unroll
  for (int g = 0; g < 4; ++g){
    int base = i0 + w * 16 + g * 4;         // 4 consecutive rows
    if (base >= s1) break;
    const float* p0 = Mat + ((size_t)b * SMax + base) * SMax;
    const float* p1 = Mat + ((size_t)b * SMax + (base + 1 < s1 ? base + 1 : base)) * SMax;
    const float* p2 = Mat + ((size_t)b * SMax + (base + 2 < s1 ? base + 2 : base)) * SMax;
    const float* p3 = Mat + ((size_t)b * SMax + (base + 3 < s1 ? base + 3 : base)) * SMax;
    float a0 = 0, a1 = 0, a2 = 0, a3 = 0;
    #pragma unroll
    for (int c = 0; c < 8; ++c){
      int idx = lane + 64 * c;
      float v = vs[idx];
      a0 = fmaf(p0[idx], v, a0);
      a1 = fmaf(p1[idx], v, a1);
      a2 = fmaf(p2[idx], v, a2);
      a3 = fmaf(p3[idx], v, a3);
    }
    #pragma unroll
    for (int off = 32; off > 0; off >>= 1){
      a0 += __shfl_xor(a0, off); a1 += __shfl_xor(a1, off);
      a2 += __shfl_xor(a2, off); a3 += __shfl_xor(a3, off);
    }
    if (lane == 0){
      float av[4] = {a0, a1, a2, a3};
      #pragma unroll
      for (int r = 0; r < 4; ++r){
        int i = base + r;
        if (i < s1)
          out[(size_t)b * SMax + i] = sgn * av[r] + (addsrc ? addsrc[(size_t)b * SMax + i] : 0.0f);
      }
    }
  }
}

// ---------------------------------------------------------------- top-32 threshold, new residual, convergence
__global__ __launch_bounds__(1024) void k_finish(const float* __restrict__ Zz, const float* __restrict__ At,
        const float* __restrict__ Y, const int* __restrict__ Cols, const int* __restrict__ Snew,
        int* __restrict__ Done, float* __restrict__ XKval, int* __restrict__ XKcol, float* __restrict__ Rres){
  int b = blockIdx.x;
  if (Done[b]) return;
  int s1 = Snew[b];
  __shared__ unsigned long long sk[SMax];
  __shared__ float xv[KKv];
  __shared__ int   xc[KKv];
  __shared__ float red[16];
  int tid = threadIdx.x;
  if (tid < SMax){
    unsigned long long key = 0;
    if (tid < s1){
      float z = Zz[(size_t)b * SMax + tid];
      unsigned int ab = __float_as_uint(fabsf(z));
      int col = Cols[b * SMax + tid];
      key = ((unsigned long long)ab << 32) | ((unsigned long long)(4095 - col) << 20) | (unsigned int)tid;
    }
    sk[tid] = key;
  }
  __syncthreads();
  for (int ksz = 2; ksz <= SMax; ksz <<= 1){
    for (int jsz = ksz >> 1; jsz > 0; jsz >>= 1){
      for (int t = tid; t < SMax / 2; t += 1024){
        int i = 2 * t - (t & (jsz - 1));
        int ixj = i ^ jsz;
        unsigned long long a = sk[i], c = sk[ixj];
        bool sw = ((i & ksz) == 0) ? (a < c) : (a > c);
        if (sw){ sk[i] = c; sk[ixj] = a; }
      }
      __syncthreads();
    }
  }
  if (tid < KKv){
    unsigned long long key = sk[tid];
    int p = (int)(key & 0xFFFFFu);
    float v = Zz[(size_t)b * SMax + p];
    xv[tid] = v;
    xc[tid] = Cols[b * SMax + p];
    XKval[b * KKv + tid] = v;
    XKcol[b * KKv + tid] = xc[tid];
  }
  __syncthreads();
  float r = Y[(size_t)b * Mdim + tid];
  for (int t = 0; t < KKv; ++t)
    r = fmaf(-xv[t], At[(size_t)xc[t] * Mdim + tid], r);
  Rres[(size_t)b * Mdim + tid] = r;
  float ss = r * r;
  #pragma unroll
  for (int off = 32; off > 0; off >>= 1) ss += __shfl_xor(ss, off);
  if ((tid & 63) == 0) red[tid >> 6] = ss;
  __syncthreads();
  if (tid == 0){
    float tot = 0;
    for (int w = 0; w < 16; ++w) tot += red[w];
    if (tot < 1e-12f) Done[b] = 1;
  }
}

// ---------------------------------------------------------------- dense output
__global__ __launch_bounds__(1024) void k_output(const float* __restrict__ XKval, const int* __restrict__ XKcol,
        float* __restrict__ out){
  int b = blockIdx.x;
  __shared__ float xv[KKv];
  __shared__ int   xc[KKv];
  if (threadIdx.x < KKv){
    xv[threadIdx.x] = XKval[b * KKv + threadIdx.x];
    xc[threadIdx.x] = XKcol[b * KKv + threadIdx.x];
  }
  __syncthreads();
  int j = blockIdx.y * 1024 + threadIdx.x;
  float v = 0.0f;
  #pragma unroll
  for (int t = 0; t < KKv; ++t) v = (xc[t] == j) ? xv[t] : v;
  out[(size_t)b * Ndim + j] = v;
}

// ----------------------------------------------------------------
extern "C" void kernel_launch(void* const* d_in, const int* in_sizes, int n_in,
                              void* d_out, int out_size, void* d_ws, size_t ws_size,
                              hipStream_t stream){
  const float* Y = (const float*)d_in[0];   // [B][M]
  const float* A = (const float*)d_in[1];   // [M][N]
  float* ws = (float*)d_ws;
  size_t off = 0;
  float* At   = ws + off; off += (size_t)Ndim * Mdim;
  float* G    = ws + off; off += (size_t)Bdim * SMax * SMax;
  float* Gi   = ws + off; off += (size_t)Bdim * SMax * SMax;
  float* V    = ws + off; off += (size_t)Bdim * SMax * K2v;
  float* T    = ws + off; off += (size_t)Bdim * SMax * K2v;
  float* Si   = ws + off; off += (size_t)Bdim * K2v * K2v;
  float* PP   = ws + off; off += (size_t)PQ * Bdim * Ndim;   // also reused as SP (Schur partials)
  float* Rres = ws + off; off += (size_t)Bdim * Mdim;
  float* Bv   = ws + off; off += (size_t)Bdim * SMax;
  float* Z0   = ws + off; off += (size_t)Bdim * SMax;
  float* R2   = ws + off; off += (size_t)Bdim * SMax;
  float* Zz   = ws + off; off += (size_t)Bdim * SMax;
  float* XKval = ws + off; off += (size_t)Bdim * KKv;
  int* XKcol = (int*)(ws + off); off += (size_t)Bdim * KKv;
  int* Cols  = (int*)(ws + off); off += (size_t)Bdim * SMax;
  int* Flags = (int*)(ws + off); off += (size_t)Bdim * Ndim;
  int* Sold  = (int*)(ws + off); off += Bdim;
  int* Snew  = (int*)(ws + off); off += Bdim;
  int* Done  = (int*)(ws + off); off += Bdim;
  float* SP = PP;   // PP is dead between topk(t) and proxy(t+1) -> reuse as Schur partials

  k_init<<<256, 256, 0, stream>>>(Y, Rres, Flags, Sold, Snew, Done);
  k_transpose<<<dim3(Ndim / 32, Mdim / 32), dim3(32, 8), 0, stream>>>(A, At);
  for (int t = 0; t < NIT; ++t){
    k_proxy<<<dim3(Ndim / 256, PQ), 256, 0, stream>>>(A, Rres, PP);
    k_topk<<<Bdim, 1024, 0, stream>>>(PP, Flags, Cols, Sold, Snew, Done);
    k_gram<<<dim3(Bdim, 16, 2), 256, 0, stream>>>(At, Y, G, Bv, Cols, Sold, Snew, Done);
    if (t > 0)
      k_V<<<dim3(Bdim, t), 256, 0, stream>>>(G, Gi, V, SP, Sold, Snew, Done);
    k_schur<<<Bdim, 256, 0, stream>>>(G, SP, Si, Sold, Snew, Done);
    if (t > 0)
      k_T<<<dim3(Bdim, t), 256, 0, stream>>>(V, Si, T, Sold, Snew, Done);
    k_upd<<<dim3(Bdim, t + 1, t + 1), 256, 0, stream>>>(Gi, T, V, Si, Sold, Snew, Done);
    k_gemv<<<dim3(Bdim, 8), 256, 0, stream>>>(Gi, Bv, nullptr, Z0, 1.0f, Snew, Done);
    k_gemv<<<dim3(Bdim, 8), 256, 0, stream>>>(G, Z0, Bv, R2, -1.0f, Snew, Done);
    k_gemv<<<dim3(Bdim, 8), 256, 0, stream>>>(Gi, R2, Z0, Zz, 1.0f, Snew, Done);
    k_finish<<<Bdim, 1024, 0, stream>>>(Zz, At, Y, Cols, Snew, Done, XKval, XKcol, Rres);
  }
  k_output<<<dim3(Bdim, Ndim / 1024), 1024, 0, stream>>>(XKval, XKcol, (float*)d_out);
}